// Round 2
// baseline (1013.187 us; speedup 1.0000x reference)
//
#include <hip/hip_runtime.h>
#include <hip/hip_bf16.h>
#include <hip/hip_fp16.h>

#define NN 50000
#define EE 800000
#define ETOT 850000
#define NG 500
#define NBLK ((NN + 255) / 256)  // 196
#define EB ((ETOT + 255) / 256)  // 3321
#define NU ((NN + 31) / 32)      // 1563 work units of 32 dst nodes

typedef __attribute__((ext_vector_type(8))) short bf16x8;
typedef __attribute__((ext_vector_type(4))) float f32x4;
typedef _Float16 h2f __attribute__((ext_vector_type(2)));

__device__ __forceinline__ h2f as_h2(unsigned u) {
    union { unsigned u; h2f h; } x;
    x.u = u;
    return x.h;
}

__device__ __forceinline__ unsigned short bf16_rne(float v) {
    unsigned u = __float_as_uint(v);
    unsigned r = u + 0x7FFFu + ((u >> 16) & 1u);
    return (unsigned short)(r >> 16);
}

// Per-block int64/int32 detect: node ids < 50000 => int64 has all-odd-words 0.
__device__ __forceinline__ int detect_stride(const int* __restrict__ ei,
                                             int tid, int* sflag) {
    if (tid < 64) {
        unsigned long long b = __ballot(ei[2 * tid + 1] != 0);
        if (tid == 0) *sflag = b ? 1 : 2;
    }
    __syncthreads();
    return *sflag;
}

// W [K][256] fp32 -> transposed, column-permuted bf16 hi/lo planes [256][K];
// permuted col j = dim*4+head. Also permuted a_src/a_dst.
__device__ __forceinline__ void prepw_one(const float* __restrict__ W,
                                          const float* __restrict__ asrc,
                                          const float* __restrict__ adst,
                                          unsigned short* __restrict__ bhi,
                                          unsigned short* __restrict__ blo,
                                          float* __restrict__ ap,
                                          float* __restrict__ adp,
                                          int K, int t) {
    int j = t / K, k = t - j * K;
    int d = j >> 2, h = j & 3;
    float v = W[k * 256 + h * 64 + d];
    unsigned short hb = bf16_rne(v);
    float hf = __uint_as_float((unsigned)hb << 16);
    bhi[t] = hb;
    blo[t] = bf16_rne(v - hf);
    if (k == 0) { ap[j] = asrc[h * 64 + d]; adp[j] = adst[h * 64 + d]; }
}

// Edge prep (int32 src/dst + self-loops + degree histogram) fused with
// both layers' weight prep in the tail blocks.
__global__ __launch_bounds__(256) void k_prep(
        const int* __restrict__ ei, int* __restrict__ src32,
        int* __restrict__ dst32, int* __restrict__ deg,
        const float* __restrict__ W1, const float* __restrict__ a1s,
        const float* __restrict__ a1d, const float* __restrict__ W2,
        const float* __restrict__ a2s, const float* __restrict__ a2d,
        unsigned short* __restrict__ b1h, unsigned short* __restrict__ b1l,
        unsigned short* __restrict__ b2h, unsigned short* __restrict__ b2l,
        float* __restrict__ ap1, float* __restrict__ adp1,
        float* __restrict__ ap2, float* __restrict__ adp2) {
    int blk = blockIdx.x;
    if (blk >= EB) {  // weight-prep tail
        int g = blk - EB;
        if (g < 128)
            prepw_one(W1, a1s, a1d, b1h, b1l, ap1, adp1, 128, g * 256 + threadIdx.x);
        else
            prepw_one(W2, a2s, a2d, b2h, b2l, ap2, adp2, 64, (g - 128) * 256 + threadIdx.x);
        return;
    }
    __shared__ int sflag;
    int tid = threadIdx.x;
    int st = detect_stride(ei, tid, &sflag);
    int e = blk * 256 + tid;
    if (e >= ETOT) return;
    int s, d;
    if (e < EE) {
        s = ei[(size_t)st * e];
        d = ei[(size_t)st * (EE + e)];
    } else {
        s = d = e - EE;  // self-loop
    }
    src32[e] = s;
    dst32[e] = d;
    atomicAdd(&deg[d], 1);
}

__global__ __launch_bounds__(256) void k_blocksum(const int* __restrict__ deg,
                                                  int* __restrict__ bsum) {
    __shared__ int l[256];
    int gid = blockIdx.x * 256 + threadIdx.x;
    int tid = threadIdx.x;
    l[tid] = (gid < NN) ? deg[gid] : 0;
    __syncthreads();
    for (int o = 128; o > 0; o >>= 1) {
        if (tid < o) l[tid] += l[tid + o];
        __syncthreads();
    }
    if (tid == 0) bsum[blockIdx.x] = l[0];
}

// Each block re-scans bsum[196] locally, then scans its 256-chunk of deg.
__global__ __launch_bounds__(256) void k_scan_final(const int* __restrict__ deg,
                                                    const int* __restrict__ bsum,
                                                    int* __restrict__ rowptr,
                                                    int* __restrict__ cursor) {
    __shared__ int lb[256];
    __shared__ int l[256];
    int tid = threadIdx.x;
    int vb = (tid < NBLK) ? bsum[tid] : 0;
    lb[tid] = vb;
    __syncthreads();
    for (int d = 1; d < 256; d <<= 1) {
        int t = (tid >= d) ? lb[tid - d] : 0;
        __syncthreads();
        lb[tid] += t;
        __syncthreads();
    }
    int boffb = lb[blockIdx.x] - bsum[blockIdx.x];
    int gid = blockIdx.x * 256 + tid;
    int v = (gid < NN) ? deg[gid] : 0;
    l[tid] = v;
    __syncthreads();
    for (int d = 1; d < 256; d <<= 1) {
        int t = (tid >= d) ? l[tid - d] : 0;
        __syncthreads();
        l[tid] += t;
        __syncthreads();
    }
    int ex = l[tid] - v + boffb;
    if (gid < NN) { rowptr[gid] = ex; cursor[gid] = ex; }
    if (gid == 0) rowptr[NN] = ETOT;
}

__global__ __launch_bounds__(256) void k_scatter(const int* __restrict__ src32,
                                                 const int* __restrict__ dst32,
                                                 int* __restrict__ cursor,
                                                 int* __restrict__ csr_src) {
    int e = blockIdx.x * 256 + threadIdx.x;
    if (e >= ETOT) return;
    int pos = atomicAdd(&cursor[dst32[e]], 1);
    csr_src[pos] = src32[e];
}

// C[M,256] = A[M,K] @ B[K,256] via MFMA 16x16x32 bf16-split (fp32-grade).
// Wave = 32 rows x 16 n-tiles: measured-best config (r12). n-split (r14),
// B-prefetch (r15), and C^T (r16) all regressed -- this shape maximizes
// per-wave B reuse at the occupancy this tiny GEMM can sustain.
// C16 is stored PANEL-MAJOR: 8 slabs of [NN][32 halves]; slab p holds
// output dims [8p,8p+8) x 4 heads, 64 B/node contiguous -> 3.2 MB slab
// fits one XCD's 4 MB L2 for the aggregation pass.
template <int K>
__global__ __launch_bounds__(64) void k_gemm_mfma(
        const float* __restrict__ A,
        const unsigned short* __restrict__ Bhi,
        const unsigned short* __restrict__ Blo,
        const float* __restrict__ aperm,
        const float* __restrict__ adperm,
        __half* __restrict__ C16,
        float* __restrict__ os,
        float* __restrict__ od, int M) {
    const int NC = K / 32;
    int lane = threadIdx.x;
    int l = lane & 15, q = lane >> 4;
    int m0 = blockIdx.x * 32;

    bf16x8 ahi[2][NC], alo[2][NC];
#pragma unroll
    for (int t = 0; t < 2; ++t) {
        int row = m0 + t * 16 + l;
        if (row >= M) row = M - 1;  // clamp loads; stores guarded below
        const float* arow = A + (size_t)row * K + q * 8;
#pragma unroll
        for (int c = 0; c < NC; ++c) {
            float4 v0 = *(const float4*)(arow + c * 32);
            float4 v1 = *(const float4*)(arow + c * 32 + 4);
            float vv[8] = {v0.x, v0.y, v0.z, v0.w, v1.x, v1.y, v1.z, v1.w};
#pragma unroll
            for (int j = 0; j < 8; ++j) {
                unsigned short hb = bf16_rne(vv[j]);
                float hf = __uint_as_float((unsigned)hb << 16);
                ahi[t][c][j] = (short)hb;
                alo[t][c][j] = (short)bf16_rne(vv[j] - hf);
            }
        }
    }

    float ps[2][4] = {}, pd[2][4] = {};
    const size_t brow = (size_t)l * K + q * 8;
#pragma unroll 2
    for (int n = 0; n < 16; ++n) {
        const unsigned short* bh = Bhi + (size_t)(n * 16) * K + brow;
        const unsigned short* bl = Blo + (size_t)(n * 16) * K + brow;
        bf16x8 bhf[NC], blf[NC];
#pragma unroll
        for (int c = 0; c < NC; ++c) {
            bhf[c] = *(const bf16x8*)(bh + c * 32);
            blf[c] = *(const bf16x8*)(bl + c * 32);
        }
        f32x4 acc0 = {0.f, 0.f, 0.f, 0.f}, acc1 = {0.f, 0.f, 0.f, 0.f};
#pragma unroll
        for (int c = 0; c < NC; ++c) {
            acc0 = __builtin_amdgcn_mfma_f32_16x16x32_bf16(ahi[0][c], bhf[c], acc0, 0, 0, 0);
            acc1 = __builtin_amdgcn_mfma_f32_16x16x32_bf16(ahi[1][c], bhf[c], acc1, 0, 0, 0);
            acc0 = __builtin_amdgcn_mfma_f32_16x16x32_bf16(ahi[0][c], blf[c], acc0, 0, 0, 0);
            acc1 = __builtin_amdgcn_mfma_f32_16x16x32_bf16(ahi[1][c], blf[c], acc1, 0, 0, 0);
            acc0 = __builtin_amdgcn_mfma_f32_16x16x32_bf16(alo[0][c], bhf[c], acc0, 0, 0, 0);
            acc1 = __builtin_amdgcn_mfma_f32_16x16x32_bf16(alo[1][c], bhf[c], acc1, 0, 0, 0);
        }
        float av = aperm[n * 16 + l], dv = adperm[n * 16 + l];
        // panel-major C address: col j=n*16+l -> slab n>>1, word (n&1)*16+l
        size_t pb = (size_t)(n >> 1) * ((size_t)NN * 32) + (size_t)(n & 1) * 16 + l;
#pragma unroll
        for (int r = 0; r < 4; ++r) {
            ps[0][r] += acc0[r] * av; pd[0][r] += acc0[r] * dv;
            ps[1][r] += acc1[r] * av; pd[1][r] += acc1[r] * dv;
            int gm0 = m0 + q * 4 + r;
            if (gm0 < M) C16[pb + (size_t)gm0 * 32] = __float2half(acc0[r]);
            int gm1 = m0 + 16 + q * 4 + r;
            if (gm1 < M) C16[pb + (size_t)gm1 * 32] = __float2half(acc1[r]);
        }
    }
#pragma unroll
    for (int t = 0; t < 2; ++t)
#pragma unroll
        for (int r = 0; r < 4; ++r) {
            ps[t][r] += __shfl_xor(ps[t][r], 4);
            ps[t][r] += __shfl_xor(ps[t][r], 8);
            pd[t][r] += __shfl_xor(pd[t][r], 4);
            pd[t][r] += __shfl_xor(pd[t][r], 8);
        }
    if (l < 4) {
#pragma unroll
        for (int t = 0; t < 2; ++t)
#pragma unroll
            for (int r = 0; r < 4; ++r) {
                int gm = m0 + t * 16 + q * 4 + r;
                if (gm < M) {
                    os[(size_t)gm * 4 + l] = ps[t][r];
                    od[(size_t)gm * 4 + l] = pd[t][r];
                }
            }
    }
}

__device__ __forceinline__ float lrelu_exp(float x) {
    x = x > 0.f ? x : 0.2f * x;
    return __expf(x);
}

// Edge-softmax precompute: wave per dst, lane per edge. Gathers as_[s]
// (800 KB, L2-resident), computes u=exp(lrelu(.)), reduces denom, writes
// NORMALIZED fp16 alpha[E][4] (already scaled by 0.25 head-mean).
__global__ __launch_bounds__(256) void k_alpha(const int* __restrict__ rowptr,
                                               const int* __restrict__ csr_src,
                                               const float* __restrict__ as_,
                                               const float* __restrict__ ad_,
                                               __half* __restrict__ alpha16) {
    int w = threadIdx.x >> 6;
    int lane = threadIdx.x & 63;
    int d = blockIdx.x * 4 + w;
    if (d >= NN) return;
    int beg = rowptr[d], end = rowptr[d + 1];
    float4 adv = *(const float4*)(ad_ + d * 4);
    float4 u0 = make_float4(0.f, 0.f, 0.f, 0.f);
    float4 den = make_float4(0.f, 0.f, 0.f, 0.f);
    int i0 = beg + lane;
    if (i0 < end) {
        int s = csr_src[i0];
        float4 sv = *(const float4*)(as_ + s * 4);
        u0.x = lrelu_exp(sv.x + adv.x);
        u0.y = lrelu_exp(sv.y + adv.y);
        u0.z = lrelu_exp(sv.z + adv.z);
        u0.w = lrelu_exp(sv.w + adv.w);
        den = u0;
    }
    for (int i = i0 + 64; i < end; i += 64) {
        int s = csr_src[i];
        float4 sv = *(const float4*)(as_ + s * 4);
        float4 u;
        u.x = lrelu_exp(sv.x + adv.x);
        u.y = lrelu_exp(sv.y + adv.y);
        u.z = lrelu_exp(sv.z + adv.z);
        u.w = lrelu_exp(sv.w + adv.w);
        __half2 q0 = __floats2half2_rn(fminf(u.x, 60000.f), fminf(u.y, 60000.f));
        __half2 q1 = __floats2half2_rn(fminf(u.z, 60000.f), fminf(u.w, 60000.f));
        *(uint2*)(alpha16 + (size_t)i * 4) = make_uint2(*(unsigned*)&q0, *(unsigned*)&q1);
        den.x += u.x; den.y += u.y; den.z += u.z; den.w += u.w;
    }
#pragma unroll
    for (int off = 32; off > 0; off >>= 1) {
        den.x += __shfl_xor(den.x, off);
        den.y += __shfl_xor(den.y, off);
        den.z += __shfl_xor(den.z, off);
        den.w += __shfl_xor(den.w, off);
    }
    float4 dinv = make_float4(0.25f / den.x, 0.25f / den.y,
                              0.25f / den.z, 0.25f / den.w);
    if (i0 < end) {
        __half2 q0 = __floats2half2_rn(u0.x * dinv.x, u0.y * dinv.y);
        __half2 q1 = __floats2half2_rn(u0.z * dinv.z, u0.w * dinv.w);
        *(uint2*)(alpha16 + (size_t)i0 * 4) = make_uint2(*(unsigned*)&q0, *(unsigned*)&q1);
    }
    for (int i = i0 + 64; i < end; i += 64) {
        uint2 r = *(const uint2*)(alpha16 + (size_t)i * 4);
        float2 fa = __half22float2(*(const __half2*)&r.x);
        float2 fb = __half22float2(*(const __half2*)&r.y);
        __half2 q0 = __floats2half2_rn(fa.x * dinv.x, fa.y * dinv.y);
        __half2 q1 = __floats2half2_rn(fb.x * dinv.z, fb.y * dinv.w);
        *(uint2*)(alpha16 + (size_t)i * 4) = make_uint2(*(unsigned*)&q0, *(unsigned*)&q1);
    }
}

// Persistent XCD-affine panel aggregation. Each block reads its REAL XCD id
// (s_getreg HW_REG_XCC_ID) and drains work units (32 dst nodes) from that
// panel's atomic cursor, so panel p's 3.2 MB slab stays resident in XCD p's
// 4 MB L2 regardless of dispatch drift (the r1 failure mode). After its own
// panel is drained it steals from the other panels -- completion (and thus
// correctness) never depends on the block->XCD mapping, only locality does.
__global__ __launch_bounds__(256) void k_aggr_xcd(
        const int* __restrict__ rowptr, const int* __restrict__ csr_src,
        const __half* __restrict__ alpha16, const __half* __restrict__ hp,
        const float* __restrict__ bias, float* __restrict__ out,
        int* __restrict__ cur) {
    __shared__ int sh_t;
    unsigned xcc;
    asm volatile("s_getreg_b32 %0, hwreg(HW_REG_XCC_ID)" : "=s"(xcc));
    int p0 = (int)(xcc & 7u);
    int w = threadIdx.x >> 6, lane = threadIdx.x & 63;
    int e8 = lane >> 3, dim8 = lane & 7;
    for (int pp = 0; pp < 8; ++pp) {
        int p = (p0 + pp) & 7;
        const __half* hsl = hp + (size_t)p * ((size_t)NN * 32) + dim8 * 4;
        float bv = bias[p * 8 + dim8];
        for (;;) {
            if (threadIdx.x == 0) sh_t = atomicAdd(&cur[p], 1);
            __syncthreads();
            int t = sh_t;
            __syncthreads();
            if (t >= NU) break;
            int d0 = t * 32 + w * 8;
            for (int k = 0; k < 8; ++k) {
                int d = d0 + k;
                if (d >= NN) break;
                int beg = rowptr[d], end = rowptr[d + 1];
                float acc = 0.f;
                int i = beg + e8;
                bool ok = i < end;
                int s = 0;
                uint2 a2 = make_uint2(0u, 0u);
                if (ok) {
                    s = csr_src[i];
                    a2 = *(const uint2*)(alpha16 + (size_t)i * 4);
                }
                while (__any(ok)) {
                    int i2 = i + 8;
                    bool ok2 = i2 < end;
                    int s2 = 0;
                    uint2 a22 = make_uint2(0u, 0u);
                    if (ok2) {
                        s2 = csr_src[i2];
                        a22 = *(const uint2*)(alpha16 + (size_t)i2 * 4);
                    }
                    if (ok) {
                        uint2 hv = *(const uint2*)(hsl + (size_t)s * 32);
                        acc = __builtin_amdgcn_fdot2(as_h2(hv.x), as_h2(a2.x), acc, false);
                        acc = __builtin_amdgcn_fdot2(as_h2(hv.y), as_h2(a2.y), acc, false);
                    }
                    i = i2; ok = ok2; s = s2; a2 = a22;
                }
                acc += __shfl_xor(acc, 8);
                acc += __shfl_xor(acc, 16);
                acc += __shfl_xor(acc, 32);
                if (e8 == 0) {
                    float v = acc + bv;
                    out[(size_t)d * 64 + p * 8 + dim8] = v > 0.f ? v : 0.f;
                }
            }
        }
    }
}

// batch is SORTED: binary-search per graph; 4 waves split the node loop.
__global__ __launch_bounds__(256) void k_pool_fc(const float* __restrict__ x3,
                                                 const int* __restrict__ batch,
                                                 const int* __restrict__ ei,
                                                 const float* __restrict__ fcW,
                                                 const float* __restrict__ fcb,
                                                 float* __restrict__ out) {
    __shared__ int sflag;
    int tid = threadIdx.x, lane = tid & 63, w = tid >> 6;
    int st = detect_stride(ei, tid, &sflag);
    int g = blockIdx.x;
    int lo = 0, hi = NN;
    while (lo < hi) { int mid = (lo + hi) >> 1; if (batch[(size_t)st * mid] < g) lo = mid + 1; else hi = mid; }
    int start = lo;
    hi = NN;
    while (lo < hi) { int mid = (lo + hi) >> 1; if (batch[(size_t)st * mid] < g + 1) lo = mid + 1; else hi = mid; }
    int end = lo;
    float sum = 0.f;
    for (int n = start + w; n < end; n += 4) sum += x3[n * 64 + lane];
    __shared__ float ls[4][64];
    ls[w][lane] = sum;
    __syncthreads();
    if (w == 0) {
        float c = (float)(end - start);
        if (c < 1.f) c = 1.f;
        float p = (ls[0][lane] + ls[1][lane] + ls[2][lane] + ls[3][lane]) / c;
#pragma unroll
        for (int o = 0; o < 16; ++o) {
            float v = p * fcW[lane * 16 + o];
#pragma unroll
            for (int off = 32; off > 0; off >>= 1) v += __shfl_down(v, off);
            if (lane == 0) out[g * 16 + o] = v + fcb[o];
        }
    }
}

extern "C" void kernel_launch(void* const* d_in, const int* in_sizes, int n_in,
                              void* d_out, int out_size, void* d_ws, size_t ws_size,
                              hipStream_t stream) {
    const float* x   = (const float*)d_in[0];
    const int*   ei  = (const int*)d_in[1];
    const int*   bat = (const int*)d_in[2];
    const float* W1  = (const float*)d_in[3];
    const float* a1s = (const float*)d_in[4];
    const float* a1d = (const float*)d_in[5];
    const float* b1  = (const float*)d_in[6];
    const float* W2  = (const float*)d_in[7];
    const float* a2s = (const float*)d_in[8];
    const float* a2d = (const float*)d_in[9];
    const float* b2  = (const float*)d_in[10];
    const float* fcW = (const float*)d_in[11];
    const float* fcb = (const float*)d_in[12];
    float* out = (float*)d_out;

    float* ws = (float*)d_ws;
    __half* h16  = (__half*)(ws + 256);           // [8][N][32] fp16 panel slabs
    float* as_   = (float*)(h16 + (size_t)NN * 256);  // [N,4]
    float* ad_   = as_ + NN * 4;                  // [N,4]
    float* xacc  = ad_ + NN * 4;                  // [N,64]
    int* src32   = (int*)(xacc + (size_t)NN * 64);// [E]
    int* dst32   = src32 + ETOT;                  // [E]
    int* deg     = dst32 + ETOT;                  // [N]
    int* rowptr  = deg + NN;                      // [N+1]
    int* cursor  = rowptr + NN + 1;               // [N]
    int* csr_src = cursor + NN;                   // [E]
    int* bsum    = csr_src + ETOT;                // [NBLK]
    char* p = (char*)(bsum + NBLK);
    p = (char*)(((size_t)p + 255) & ~(size_t)255);
    unsigned short* bt1h = (unsigned short*)p; p += 256 * 128 * 2;
    unsigned short* bt1l = (unsigned short*)p; p += 256 * 128 * 2;
    unsigned short* bt2h = (unsigned short*)p; p += 256 * 64 * 2;
    unsigned short* bt2l = (unsigned short*)p; p += 256 * 64 * 2;
    float* ap1  = (float*)p; p += 256 * 4;
    float* adp1 = (float*)p; p += 256 * 4;
    float* ap2  = (float*)p; p += 256 * 4;
    float* adp2 = (float*)p; p += 256 * 4;
    p = (char*)(((size_t)p + 255) & ~(size_t)255);
    __half* alpha16 = (__half*)p; p += (size_t)ETOT * 4 * 2;  // [E][4] fp16
    p = (char*)(((size_t)p + 255) & ~(size_t)255);
    int* curs = (int*)p; p += 16 * 4;             // per-panel cursors x2 layers

    const int wb = (NN + 3) / 4;  // 12500 wave-per-node blocks (k_alpha)

    // ---- one-time per call: indices + dst-CSR + weight planes ----
    hipMemsetAsync(deg, 0, NN * sizeof(int), stream);
    hipMemsetAsync(curs, 0, 16 * sizeof(int), stream);
    k_prep<<<EB + 192, 256, 0, stream>>>(ei, src32, dst32, deg,
                                         W1, a1s, a1d, W2, a2s, a2d,
                                         bt1h, bt1l, bt2h, bt2l,
                                         ap1, adp1, ap2, adp2);
    k_blocksum<<<NBLK, 256, 0, stream>>>(deg, bsum);
    k_scan_final<<<NBLK, 256, 0, stream>>>(deg, bsum, rowptr, cursor);
    k_scatter<<<EB, 256, 0, stream>>>(src32, dst32, cursor, csr_src);

    const int gg = (NN + 31) / 32;  // 1563 single-wave blocks, 32 rows each
    // ---- layer 1 ----
    k_gemm_mfma<128><<<gg, 64, 0, stream>>>(x, bt1h, bt1l, ap1, adp1, h16, as_, ad_, NN);
    k_alpha<<<wb, 256, 0, stream>>>(rowptr, csr_src, as_, ad_, alpha16);
    k_aggr_xcd<<<2048, 256, 0, stream>>>(rowptr, csr_src, alpha16, h16, b1, xacc, curs);
    // ---- layer 2 ----
    k_gemm_mfma<64><<<gg, 64, 0, stream>>>(xacc, bt2h, bt2l, ap2, adp2, h16, as_, ad_, NN);
    k_alpha<<<wb, 256, 0, stream>>>(rowptr, csr_src, as_, ad_, alpha16);
    k_aggr_xcd<<<2048, 256, 0, stream>>>(rowptr, csr_src, alpha16, h16, b2, xacc, curs + 8);
    // ---- pool + fc ----
    k_pool_fc<<<NG, 256, 0, stream>>>(xacc, bat, ei, fcW, fcb, out);
}

// Round 3
// 877.509 us; speedup vs baseline: 1.1546x; 1.1546x over previous
//
#include <hip/hip_runtime.h>
#include <hip/hip_bf16.h>
#include <hip/hip_fp16.h>

#define NN 50000
#define EE 800000
#define ETOT 850000
#define NG 500
#define NBLK ((NN + 255) / 256)  // 196
#define EB ((ETOT + 255) / 256)  // 3321
#define NU ((NN + 31) / 32)      // 1563 claims of 32 dst nodes

typedef __attribute__((ext_vector_type(8))) short bf16x8;
typedef __attribute__((ext_vector_type(4))) float f32x4;
typedef _Float16 h2f __attribute__((ext_vector_type(2)));

__device__ __forceinline__ h2f as_h2(unsigned u) {
    union { unsigned u; h2f h; } x;
    x.u = u;
    return x.h;
}

__device__ __forceinline__ unsigned short bf16_rne(float v) {
    unsigned u = __float_as_uint(v);
    unsigned r = u + 0x7FFFu + ((u >> 16) & 1u);
    return (unsigned short)(r >> 16);
}

// Per-block int64/int32 detect: node ids < 50000 => int64 has all-odd-words 0.
__device__ __forceinline__ int detect_stride(const int* __restrict__ ei,
                                             int tid, int* sflag) {
    if (tid < 64) {
        unsigned long long b = __ballot(ei[2 * tid + 1] != 0);
        if (tid == 0) *sflag = b ? 1 : 2;
    }
    __syncthreads();
    return *sflag;
}

// W [K][256] fp32 -> transposed, column-permuted bf16 hi/lo planes [256][K];
// permuted col j = dim*4+head. Also permuted a_src/a_dst.
__device__ __forceinline__ void prepw_one(const float* __restrict__ W,
                                          const float* __restrict__ asrc,
                                          const float* __restrict__ adst,
                                          unsigned short* __restrict__ bhi,
                                          unsigned short* __restrict__ blo,
                                          float* __restrict__ ap,
                                          float* __restrict__ adp,
                                          int K, int t) {
    int j = t / K, k = t - j * K;
    int d = j >> 2, h = j & 3;
    float v = W[k * 256 + h * 64 + d];
    unsigned short hb = bf16_rne(v);
    float hf = __uint_as_float((unsigned)hb << 16);
    bhi[t] = hb;
    blo[t] = bf16_rne(v - hf);
    if (k == 0) { ap[j] = asrc[h * 64 + d]; adp[j] = adst[h * 64 + d]; }
}

// Edge prep (int32 src/dst + self-loops + degree histogram) fused with
// both layers' weight prep in the tail blocks.
__global__ __launch_bounds__(256) void k_prep(
        const int* __restrict__ ei, int* __restrict__ src32,
        int* __restrict__ dst32, int* __restrict__ deg,
        const float* __restrict__ W1, const float* __restrict__ a1s,
        const float* __restrict__ a1d, const float* __restrict__ W2,
        const float* __restrict__ a2s, const float* __restrict__ a2d,
        unsigned short* __restrict__ b1h, unsigned short* __restrict__ b1l,
        unsigned short* __restrict__ b2h, unsigned short* __restrict__ b2l,
        float* __restrict__ ap1, float* __restrict__ adp1,
        float* __restrict__ ap2, float* __restrict__ adp2) {
    int blk = blockIdx.x;
    if (blk >= EB) {  // weight-prep tail
        int g = blk - EB;
        if (g < 128)
            prepw_one(W1, a1s, a1d, b1h, b1l, ap1, adp1, 128, g * 256 + threadIdx.x);
        else
            prepw_one(W2, a2s, a2d, b2h, b2l, ap2, adp2, 64, (g - 128) * 256 + threadIdx.x);
        return;
    }
    __shared__ int sflag;
    int tid = threadIdx.x;
    int st = detect_stride(ei, tid, &sflag);
    int e = blk * 256 + tid;
    if (e >= ETOT) return;
    int s, d;
    if (e < EE) {
        s = ei[(size_t)st * e];
        d = ei[(size_t)st * (EE + e)];
    } else {
        s = d = e - EE;  // self-loop
    }
    src32[e] = s;
    dst32[e] = d;
    atomicAdd(&deg[d], 1);
}

__global__ __launch_bounds__(256) void k_blocksum(const int* __restrict__ deg,
                                                  int* __restrict__ bsum) {
    __shared__ int l[256];
    int gid = blockIdx.x * 256 + threadIdx.x;
    int tid = threadIdx.x;
    l[tid] = (gid < NN) ? deg[gid] : 0;
    __syncthreads();
    for (int o = 128; o > 0; o >>= 1) {
        if (tid < o) l[tid] += l[tid + o];
        __syncthreads();
    }
    if (tid == 0) bsum[blockIdx.x] = l[0];
}

// Each block re-scans bsum[196] locally, then scans its 256-chunk of deg.
__global__ __launch_bounds__(256) void k_scan_final(const int* __restrict__ deg,
                                                    const int* __restrict__ bsum,
                                                    int* __restrict__ rowptr,
                                                    int* __restrict__ cursor) {
    __shared__ int lb[256];
    __shared__ int l[256];
    int tid = threadIdx.x;
    int vb = (tid < NBLK) ? bsum[tid] : 0;
    lb[tid] = vb;
    __syncthreads();
    for (int d = 1; d < 256; d <<= 1) {
        int t = (tid >= d) ? lb[tid - d] : 0;
        __syncthreads();
        lb[tid] += t;
        __syncthreads();
    }
    int boffb = lb[blockIdx.x] - bsum[blockIdx.x];
    int gid = blockIdx.x * 256 + tid;
    int v = (gid < NN) ? deg[gid] : 0;
    l[tid] = v;
    __syncthreads();
    for (int d = 1; d < 256; d <<= 1) {
        int t = (tid >= d) ? l[tid - d] : 0;
        __syncthreads();
        l[tid] += t;
        __syncthreads();
    }
    int ex = l[tid] - v + boffb;
    if (gid < NN) { rowptr[gid] = ex; cursor[gid] = ex; }
    if (gid == 0) rowptr[NN] = ETOT;
}

__global__ __launch_bounds__(256) void k_scatter(const int* __restrict__ src32,
                                                 const int* __restrict__ dst32,
                                                 int* __restrict__ cursor,
                                                 int* __restrict__ csr_src) {
    int e = blockIdx.x * 256 + threadIdx.x;
    if (e >= ETOT) return;
    int pos = atomicAdd(&cursor[dst32[e]], 1);
    csr_src[pos] = src32[e];
}

// C[M,256] = A[M,K] @ B[K,256] via MFMA 16x16x32 bf16-split (fp32-grade).
// Wave = 32 rows x 16 n-tiles: measured-best config (r12). n-split (r14),
// B-prefetch (r15), and C^T (r16) all regressed -- this shape maximizes
// per-wave B reuse at the occupancy this tiny GEMM can sustain.
// C16 is stored PANEL-MAJOR: 8 slabs of [NN][32 halves]; slab p holds
// output dims [8p,8p+8) x 4 heads, 64 B/node contiguous -> 3.2 MB slab
// fits one XCD's 4 MB L2 for the aggregation pass.
template <int K>
__global__ __launch_bounds__(64) void k_gemm_mfma(
        const float* __restrict__ A,
        const unsigned short* __restrict__ Bhi,
        const unsigned short* __restrict__ Blo,
        const float* __restrict__ aperm,
        const float* __restrict__ adperm,
        __half* __restrict__ C16,
        float* __restrict__ os,
        float* __restrict__ od, int M) {
    const int NC = K / 32;
    int lane = threadIdx.x;
    int l = lane & 15, q = lane >> 4;
    int m0 = blockIdx.x * 32;

    bf16x8 ahi[2][NC], alo[2][NC];
#pragma unroll
    for (int t = 0; t < 2; ++t) {
        int row = m0 + t * 16 + l;
        if (row >= M) row = M - 1;  // clamp loads; stores guarded below
        const float* arow = A + (size_t)row * K + q * 8;
#pragma unroll
        for (int c = 0; c < NC; ++c) {
            float4 v0 = *(const float4*)(arow + c * 32);
            float4 v1 = *(const float4*)(arow + c * 32 + 4);
            float vv[8] = {v0.x, v0.y, v0.z, v0.w, v1.x, v1.y, v1.z, v1.w};
#pragma unroll
            for (int j = 0; j < 8; ++j) {
                unsigned short hb = bf16_rne(vv[j]);
                float hf = __uint_as_float((unsigned)hb << 16);
                ahi[t][c][j] = (short)hb;
                alo[t][c][j] = (short)bf16_rne(vv[j] - hf);
            }
        }
    }

    float ps[2][4] = {}, pd[2][4] = {};
    const size_t brow = (size_t)l * K + q * 8;
#pragma unroll 2
    for (int n = 0; n < 16; ++n) {
        const unsigned short* bh = Bhi + (size_t)(n * 16) * K + brow;
        const unsigned short* bl = Blo + (size_t)(n * 16) * K + brow;
        bf16x8 bhf[NC], blf[NC];
#pragma unroll
        for (int c = 0; c < NC; ++c) {
            bhf[c] = *(const bf16x8*)(bh + c * 32);
            blf[c] = *(const bf16x8*)(bl + c * 32);
        }
        f32x4 acc0 = {0.f, 0.f, 0.f, 0.f}, acc1 = {0.f, 0.f, 0.f, 0.f};
#pragma unroll
        for (int c = 0; c < NC; ++c) {
            acc0 = __builtin_amdgcn_mfma_f32_16x16x32_bf16(ahi[0][c], bhf[c], acc0, 0, 0, 0);
            acc1 = __builtin_amdgcn_mfma_f32_16x16x32_bf16(ahi[1][c], bhf[c], acc1, 0, 0, 0);
            acc0 = __builtin_amdgcn_mfma_f32_16x16x32_bf16(ahi[0][c], blf[c], acc0, 0, 0, 0);
            acc1 = __builtin_amdgcn_mfma_f32_16x16x32_bf16(ahi[1][c], blf[c], acc1, 0, 0, 0);
            acc0 = __builtin_amdgcn_mfma_f32_16x16x32_bf16(alo[0][c], bhf[c], acc0, 0, 0, 0);
            acc1 = __builtin_amdgcn_mfma_f32_16x16x32_bf16(alo[1][c], bhf[c], acc1, 0, 0, 0);
        }
        float av = aperm[n * 16 + l], dv = adperm[n * 16 + l];
        // panel-major C address: col j=n*16+l -> slab n>>1, word (n&1)*16+l
        size_t pb = (size_t)(n >> 1) * ((size_t)NN * 32) + (size_t)(n & 1) * 16 + l;
#pragma unroll
        for (int r = 0; r < 4; ++r) {
            ps[0][r] += acc0[r] * av; pd[0][r] += acc0[r] * dv;
            ps[1][r] += acc1[r] * av; pd[1][r] += acc1[r] * dv;
            int gm0 = m0 + q * 4 + r;
            if (gm0 < M) C16[pb + (size_t)gm0 * 32] = __float2half(acc0[r]);
            int gm1 = m0 + 16 + q * 4 + r;
            if (gm1 < M) C16[pb + (size_t)gm1 * 32] = __float2half(acc1[r]);
        }
    }
#pragma unroll
    for (int t = 0; t < 2; ++t)
#pragma unroll
        for (int r = 0; r < 4; ++r) {
            ps[t][r] += __shfl_xor(ps[t][r], 4);
            ps[t][r] += __shfl_xor(ps[t][r], 8);
            pd[t][r] += __shfl_xor(pd[t][r], 4);
            pd[t][r] += __shfl_xor(pd[t][r], 8);
        }
    if (l < 4) {
#pragma unroll
        for (int t = 0; t < 2; ++t)
#pragma unroll
            for (int r = 0; r < 4; ++r) {
                int gm = m0 + t * 16 + q * 4 + r;
                if (gm < M) {
                    os[(size_t)gm * 4 + l] = ps[t][r];
                    od[(size_t)gm * 4 + l] = pd[t][r];
                }
            }
    }
}

__device__ __forceinline__ float lrelu_exp(float x) {
    x = x > 0.f ? x : 0.2f * x;
    return __expf(x);
}

// Edge-softmax precompute: wave per dst, lane per edge. Gathers as_[s]
// (800 KB, L2-resident), computes u=exp(lrelu(.)), reduces denom, writes
// NORMALIZED fp16 alpha[E][4] (already scaled by 0.25 head-mean).
__global__ __launch_bounds__(256) void k_alpha(const int* __restrict__ rowptr,
                                               const int* __restrict__ csr_src,
                                               const float* __restrict__ as_,
                                               const float* __restrict__ ad_,
                                               __half* __restrict__ alpha16) {
    int w = threadIdx.x >> 6;
    int lane = threadIdx.x & 63;
    int d = blockIdx.x * 4 + w;
    if (d >= NN) return;
    int beg = rowptr[d], end = rowptr[d + 1];
    float4 adv = *(const float4*)(ad_ + d * 4);
    float4 u0 = make_float4(0.f, 0.f, 0.f, 0.f);
    float4 den = make_float4(0.f, 0.f, 0.f, 0.f);
    int i0 = beg + lane;
    if (i0 < end) {
        int s = csr_src[i0];
        float4 sv = *(const float4*)(as_ + s * 4);
        u0.x = lrelu_exp(sv.x + adv.x);
        u0.y = lrelu_exp(sv.y + adv.y);
        u0.z = lrelu_exp(sv.z + adv.z);
        u0.w = lrelu_exp(sv.w + adv.w);
        den = u0;
    }
    for (int i = i0 + 64; i < end; i += 64) {
        int s = csr_src[i];
        float4 sv = *(const float4*)(as_ + s * 4);
        float4 u;
        u.x = lrelu_exp(sv.x + adv.x);
        u.y = lrelu_exp(sv.y + adv.y);
        u.z = lrelu_exp(sv.z + adv.z);
        u.w = lrelu_exp(sv.w + adv.w);
        __half2 q0 = __floats2half2_rn(fminf(u.x, 60000.f), fminf(u.y, 60000.f));
        __half2 q1 = __floats2half2_rn(fminf(u.z, 60000.f), fminf(u.w, 60000.f));
        *(uint2*)(alpha16 + (size_t)i * 4) = make_uint2(*(unsigned*)&q0, *(unsigned*)&q1);
        den.x += u.x; den.y += u.y; den.z += u.z; den.w += u.w;
    }
#pragma unroll
    for (int off = 32; off > 0; off >>= 1) {
        den.x += __shfl_xor(den.x, off);
        den.y += __shfl_xor(den.y, off);
        den.z += __shfl_xor(den.z, off);
        den.w += __shfl_xor(den.w, off);
    }
    float4 dinv = make_float4(0.25f / den.x, 0.25f / den.y,
                              0.25f / den.z, 0.25f / den.w);
    if (i0 < end) {
        __half2 q0 = __floats2half2_rn(u0.x * dinv.x, u0.y * dinv.y);
        __half2 q1 = __floats2half2_rn(u0.z * dinv.z, u0.w * dinv.w);
        *(uint2*)(alpha16 + (size_t)i0 * 4) = make_uint2(*(unsigned*)&q0, *(unsigned*)&q1);
    }
    for (int i = i0 + 64; i < end; i += 64) {
        uint2 r = *(const uint2*)(alpha16 + (size_t)i * 4);
        float2 fa = __half22float2(*(const __half2*)&r.x);
        float2 fb = __half22float2(*(const __half2*)&r.y);
        __half2 q0 = __floats2half2_rn(fa.x * dinv.x, fa.y * dinv.y);
        __half2 q1 = __floats2half2_rn(fb.x * dinv.z, fb.y * dinv.w);
        *(uint2*)(alpha16 + (size_t)i * 4) = make_uint2(*(unsigned*)&q0, *(unsigned*)&q1);
    }
}

// Persistent XCD-affine panel aggregation, v2 (TLP-restoring rewrite of r2):
// - per-WAVE claims (lane-0 atomicAdd + shfl broadcast), NO __syncthreads
//   anywhere -> 8192 independent waves hide the L2 gather latency;
// - cursors padded to 64 B so the 8 panel counters never share a line;
// - volatile pre-check before stealing (stale reads only under-read the
//   monotonic counter -> harmless extra atomic, never skipped work);
// - h-slice gather double-buffered one iteration ahead.
// Panel p's 3.2 MB slab stays resident in XCD p's 4 MB L2 (r2 PROVED this:
// FETCH = streams + exactly one table fill).
__global__ __launch_bounds__(256) void k_aggr_xcd(
        const int* __restrict__ rowptr, const int* __restrict__ csr_src,
        const __half* __restrict__ alpha16, const __half* __restrict__ hp,
        const float* __restrict__ bias, float* __restrict__ out,
        int* __restrict__ cur) {
    unsigned xcc;
    asm volatile("s_getreg_b32 %0, hwreg(HW_REG_XCC_ID)" : "=s"(xcc));
    int p0 = (int)(xcc & 7u);
    int lane = threadIdx.x & 63;
    int e8 = lane >> 3, dim8 = lane & 7;
    for (int pp = 0; pp < 8; ++pp) {
        int p = (p0 + pp) & 7;
        if (pp && *(volatile int*)&cur[p * 16] >= NU) continue;
        const __half* hsl = hp + (size_t)p * ((size_t)NN * 32) + dim8 * 4;
        float bv = bias[p * 8 + dim8];
        for (;;) {
            int t = 0;
            if (lane == 0) t = atomicAdd(&cur[p * 16], 1);
            t = __shfl(t, 0);
            if (t >= NU) break;
            int d0 = t * 32, d1 = d0 + 32;
            if (d1 > NN) d1 = NN;
            for (int d = d0; d < d1; ++d) {
                int beg = rowptr[d], end = rowptr[d + 1];
                float acc = 0.f;
                int i = beg + e8;
                bool ok = i < end;
                uint2 a2 = make_uint2(0u, 0u), hv = make_uint2(0u, 0u);
                if (ok) {
                    int s = csr_src[i];
                    a2 = *(const uint2*)(alpha16 + (size_t)i * 4);
                    hv = *(const uint2*)(hsl + (size_t)s * 32);
                }
                while (__any(ok)) {
                    int i2 = i + 8;
                    bool ok2 = i2 < end;
                    uint2 a22 = make_uint2(0u, 0u), hv2 = make_uint2(0u, 0u);
                    if (ok2) {
                        int s2 = csr_src[i2];
                        a22 = *(const uint2*)(alpha16 + (size_t)i2 * 4);
                        hv2 = *(const uint2*)(hsl + (size_t)s2 * 32);
                    }
                    if (ok) {
                        acc = __builtin_amdgcn_fdot2(as_h2(hv.x), as_h2(a2.x), acc, false);
                        acc = __builtin_amdgcn_fdot2(as_h2(hv.y), as_h2(a2.y), acc, false);
                    }
                    i = i2; ok = ok2; a2 = a22; hv = hv2;
                }
                acc += __shfl_xor(acc, 8);
                acc += __shfl_xor(acc, 16);
                acc += __shfl_xor(acc, 32);
                if (e8 == 0) {
                    float v = acc + bv;
                    out[(size_t)d * 64 + p * 8 + dim8] = v > 0.f ? v : 0.f;
                }
            }
        }
    }
}

// batch is SORTED: binary-search per graph; 4 waves split the node loop.
__global__ __launch_bounds__(256) void k_pool_fc(const float* __restrict__ x3,
                                                 const int* __restrict__ batch,
                                                 const int* __restrict__ ei,
                                                 const float* __restrict__ fcW,
                                                 const float* __restrict__ fcb,
                                                 float* __restrict__ out) {
    __shared__ int sflag;
    int tid = threadIdx.x, lane = tid & 63, w = tid >> 6;
    int st = detect_stride(ei, tid, &sflag);
    int g = blockIdx.x;
    int lo = 0, hi = NN;
    while (lo < hi) { int mid = (lo + hi) >> 1; if (batch[(size_t)st * mid] < g) lo = mid + 1; else hi = mid; }
    int start = lo;
    hi = NN;
    while (lo < hi) { int mid = (lo + hi) >> 1; if (batch[(size_t)st * mid] < g + 1) lo = mid + 1; else hi = mid; }
    int end = lo;
    float sum = 0.f;
    for (int n = start + w; n < end; n += 4) sum += x3[n * 64 + lane];
    __shared__ float ls[4][64];
    ls[w][lane] = sum;
    __syncthreads();
    if (w == 0) {
        float c = (float)(end - start);
        if (c < 1.f) c = 1.f;
        float p = (ls[0][lane] + ls[1][lane] + ls[2][lane] + ls[3][lane]) / c;
#pragma unroll
        for (int o = 0; o < 16; ++o) {
            float v = p * fcW[lane * 16 + o];
#pragma unroll
            for (int off = 32; off > 0; off >>= 1) v += __shfl_down(v, off);
            if (lane == 0) out[g * 16 + o] = v + fcb[o];
        }
    }
}

extern "C" void kernel_launch(void* const* d_in, const int* in_sizes, int n_in,
                              void* d_out, int out_size, void* d_ws, size_t ws_size,
                              hipStream_t stream) {
    const float* x   = (const float*)d_in[0];
    const int*   ei  = (const int*)d_in[1];
    const int*   bat = (const int*)d_in[2];
    const float* W1  = (const float*)d_in[3];
    const float* a1s = (const float*)d_in[4];
    const float* a1d = (const float*)d_in[5];
    const float* b1  = (const float*)d_in[6];
    const float* W2  = (const float*)d_in[7];
    const float* a2s = (const float*)d_in[8];
    const float* a2d = (const float*)d_in[9];
    const float* b2  = (const float*)d_in[10];
    const float* fcW = (const float*)d_in[11];
    const float* fcb = (const float*)d_in[12];
    float* out = (float*)d_out;

    float* ws = (float*)d_ws;
    __half* h16  = (__half*)(ws + 256);           // [8][N][32] fp16 panel slabs
    float* as_   = (float*)(h16 + (size_t)NN * 256);  // [N,4]
    float* ad_   = as_ + NN * 4;                  // [N,4]
    float* xacc  = ad_ + NN * 4;                  // [N,64]
    int* src32   = (int*)(xacc + (size_t)NN * 64);// [E]
    int* dst32   = src32 + ETOT;                  // [E]
    int* deg     = dst32 + ETOT;                  // [N]
    int* rowptr  = deg + NN;                      // [N+1]
    int* cursor  = rowptr + NN + 1;               // [N]
    int* csr_src = cursor + NN;                   // [E]
    int* bsum    = csr_src + ETOT;                // [NBLK]
    char* p = (char*)(bsum + NBLK);
    p = (char*)(((size_t)p + 255) & ~(size_t)255);
    unsigned short* bt1h = (unsigned short*)p; p += 256 * 128 * 2;
    unsigned short* bt1l = (unsigned short*)p; p += 256 * 128 * 2;
    unsigned short* bt2h = (unsigned short*)p; p += 256 * 64 * 2;
    unsigned short* bt2l = (unsigned short*)p; p += 256 * 64 * 2;
    float* ap1  = (float*)p; p += 256 * 4;
    float* adp1 = (float*)p; p += 256 * 4;
    float* ap2  = (float*)p; p += 256 * 4;
    float* adp2 = (float*)p; p += 256 * 4;
    p = (char*)(((size_t)p + 255) & ~(size_t)255);
    __half* alpha16 = (__half*)p; p += (size_t)ETOT * 4 * 2;  // [E][4] fp16
    p = (char*)(((size_t)p + 255) & ~(size_t)255);
    int* curs = (int*)p; p += 256 * 4;  // 8 cursors x 64B pad x 2 layers

    const int wb = (NN + 3) / 4;  // 12500 wave-per-node blocks (k_alpha)

    // ---- one-time per call: indices + dst-CSR + weight planes ----
    hipMemsetAsync(deg, 0, NN * sizeof(int), stream);
    hipMemsetAsync(curs, 0, 256 * sizeof(int), stream);
    k_prep<<<EB + 192, 256, 0, stream>>>(ei, src32, dst32, deg,
                                         W1, a1s, a1d, W2, a2s, a2d,
                                         bt1h, bt1l, bt2h, bt2l,
                                         ap1, adp1, ap2, adp2);
    k_blocksum<<<NBLK, 256, 0, stream>>>(deg, bsum);
    k_scan_final<<<NBLK, 256, 0, stream>>>(deg, bsum, rowptr, cursor);
    k_scatter<<<EB, 256, 0, stream>>>(src32, dst32, cursor, csr_src);

    const int gg = (NN + 31) / 32;  // 1563 single-wave blocks, 32 rows each
    // ---- layer 1 ----
    k_gemm_mfma<128><<<gg, 64, 0, stream>>>(x, bt1h, bt1l, ap1, adp1, h16, as_, ad_, NN);
    k_alpha<<<wb, 256, 0, stream>>>(rowptr, csr_src, as_, ad_, alpha16);
    k_aggr_xcd<<<2048, 256, 0, stream>>>(rowptr, csr_src, alpha16, h16, b1, xacc, curs);
    // ---- layer 2 ----
    k_gemm_mfma<64><<<gg, 64, 0, stream>>>(xacc, bt2h, bt2l, ap2, adp2, h16, as_, ad_, NN);
    k_alpha<<<wb, 256, 0, stream>>>(rowptr, csr_src, as_, ad_, alpha16);
    k_aggr_xcd<<<2048, 256, 0, stream>>>(rowptr, csr_src, alpha16, h16, b2, xacc, curs + 128);
    // ---- pool + fc ----
    k_pool_fc<<<NG, 256, 0, stream>>>(xacc, bat, ei, fcW, fcb, out);
}

// Round 4
// 820.819 us; speedup vs baseline: 1.2344x; 1.0691x over previous
//
#include <hip/hip_runtime.h>
#include <hip/hip_bf16.h>
#include <hip/hip_fp16.h>

#define NN 50000
#define EE 800000
#define ETOT 850000
#define NG 500
#define NBLK ((NN + 255) / 256)  // 196
#define EB ((ETOT + 255) / 256)  // 3321
#define NU ((NN + 31) / 32)      // 1563 claims of 32 dst nodes
#define CH 256                   // staged edge-chunk per claim

typedef __attribute__((ext_vector_type(8))) short bf16x8;
typedef __attribute__((ext_vector_type(4))) float f32x4;
typedef _Float16 h2f __attribute__((ext_vector_type(2)));

__device__ __forceinline__ h2f as_h2(unsigned u) {
    union { unsigned u; h2f h; } x;
    x.u = u;
    return x.h;
}

__device__ __forceinline__ unsigned short bf16_rne(float v) {
    unsigned u = __float_as_uint(v);
    unsigned r = u + 0x7FFFu + ((u >> 16) & 1u);
    return (unsigned short)(r >> 16);
}

// Per-block int64/int32 detect: node ids < 50000 => int64 has all-odd-words 0.
__device__ __forceinline__ int detect_stride(const int* __restrict__ ei,
                                             int tid, int* sflag) {
    if (tid < 64) {
        unsigned long long b = __ballot(ei[2 * tid + 1] != 0);
        if (tid == 0) *sflag = b ? 1 : 2;
    }
    __syncthreads();
    return *sflag;
}

// W [K][256] fp32 -> transposed, column-permuted bf16 hi/lo planes [256][K];
// permuted col j = dim*4+head. Also permuted a_src/a_dst.
__device__ __forceinline__ void prepw_one(const float* __restrict__ W,
                                          const float* __restrict__ asrc,
                                          const float* __restrict__ adst,
                                          unsigned short* __restrict__ bhi,
                                          unsigned short* __restrict__ blo,
                                          float* __restrict__ ap,
                                          float* __restrict__ adp,
                                          int K, int t) {
    int j = t / K, k = t - j * K;
    int d = j >> 2, h = j & 3;
    float v = W[k * 256 + h * 64 + d];
    unsigned short hb = bf16_rne(v);
    float hf = __uint_as_float((unsigned)hb << 16);
    bhi[t] = hb;
    blo[t] = bf16_rne(v - hf);
    if (k == 0) { ap[j] = asrc[h * 64 + d]; adp[j] = adst[h * 64 + d]; }
}

// Edge prep (int32 src/dst + self-loops + degree histogram) fused with
// both layers' weight prep in the tail blocks.
__global__ __launch_bounds__(256) void k_prep(
        const int* __restrict__ ei, int* __restrict__ src32,
        int* __restrict__ dst32, int* __restrict__ deg,
        const float* __restrict__ W1, const float* __restrict__ a1s,
        const float* __restrict__ a1d, const float* __restrict__ W2,
        const float* __restrict__ a2s, const float* __restrict__ a2d,
        unsigned short* __restrict__ b1h, unsigned short* __restrict__ b1l,
        unsigned short* __restrict__ b2h, unsigned short* __restrict__ b2l,
        float* __restrict__ ap1, float* __restrict__ adp1,
        float* __restrict__ ap2, float* __restrict__ adp2) {
    int blk = blockIdx.x;
    if (blk >= EB) {  // weight-prep tail
        int g = blk - EB;
        if (g < 128)
            prepw_one(W1, a1s, a1d, b1h, b1l, ap1, adp1, 128, g * 256 + threadIdx.x);
        else
            prepw_one(W2, a2s, a2d, b2h, b2l, ap2, adp2, 64, (g - 128) * 256 + threadIdx.x);
        return;
    }
    __shared__ int sflag;
    int tid = threadIdx.x;
    int st = detect_stride(ei, tid, &sflag);
    int e = blk * 256 + tid;
    if (e >= ETOT) return;
    int s, d;
    if (e < EE) {
        s = ei[(size_t)st * e];
        d = ei[(size_t)st * (EE + e)];
    } else {
        s = d = e - EE;  // self-loop
    }
    src32[e] = s;
    dst32[e] = d;
    atomicAdd(&deg[d], 1);
}

__global__ __launch_bounds__(256) void k_blocksum(const int* __restrict__ deg,
                                                  int* __restrict__ bsum) {
    __shared__ int l[256];
    int gid = blockIdx.x * 256 + threadIdx.x;
    int tid = threadIdx.x;
    l[tid] = (gid < NN) ? deg[gid] : 0;
    __syncthreads();
    for (int o = 128; o > 0; o >>= 1) {
        if (tid < o) l[tid] += l[tid + o];
        __syncthreads();
    }
    if (tid == 0) bsum[blockIdx.x] = l[0];
}

// Each block re-scans bsum[196] locally, then scans its 256-chunk of deg.
__global__ __launch_bounds__(256) void k_scan_final(const int* __restrict__ deg,
                                                    const int* __restrict__ bsum,
                                                    int* __restrict__ rowptr,
                                                    int* __restrict__ cursor) {
    __shared__ int lb[256];
    __shared__ int l[256];
    int tid = threadIdx.x;
    int vb = (tid < NBLK) ? bsum[tid] : 0;
    lb[tid] = vb;
    __syncthreads();
    for (int d = 1; d < 256; d <<= 1) {
        int t = (tid >= d) ? lb[tid - d] : 0;
        __syncthreads();
        lb[tid] += t;
        __syncthreads();
    }
    int boffb = lb[blockIdx.x] - bsum[blockIdx.x];
    int gid = blockIdx.x * 256 + tid;
    int v = (gid < NN) ? deg[gid] : 0;
    l[tid] = v;
    __syncthreads();
    for (int d = 1; d < 256; d <<= 1) {
        int t = (tid >= d) ? l[tid - d] : 0;
        __syncthreads();
        l[tid] += t;
        __syncthreads();
    }
    int ex = l[tid] - v + boffb;
    if (gid < NN) { rowptr[gid] = ex; cursor[gid] = ex; }
    if (gid == 0) rowptr[NN] = ETOT;
}

__global__ __launch_bounds__(256) void k_scatter(const int* __restrict__ src32,
                                                 const int* __restrict__ dst32,
                                                 int* __restrict__ cursor,
                                                 int* __restrict__ csr_src) {
    int e = blockIdx.x * 256 + threadIdx.x;
    if (e >= ETOT) return;
    int pos = atomicAdd(&cursor[dst32[e]], 1);
    csr_src[pos] = src32[e];
}

// C[M,256] = A[M,K] @ B[K,256] via MFMA 16x16x32 bf16-split (fp32-grade).
// C16 is stored PANEL-MAJOR: 8 slabs of [NN][32 halves]; slab p holds
// output dims [8p,8p+8) x 4 heads, 64 B/node contiguous -> 3.2 MB slab
// fits one XCD's 4 MB L2 for the aggregation pass.
template <int K>
__global__ __launch_bounds__(64) void k_gemm_mfma(
        const float* __restrict__ A,
        const unsigned short* __restrict__ Bhi,
        const unsigned short* __restrict__ Blo,
        const float* __restrict__ aperm,
        const float* __restrict__ adperm,
        __half* __restrict__ C16,
        float* __restrict__ os,
        float* __restrict__ od, int M) {
    const int NC = K / 32;
    int lane = threadIdx.x;
    int l = lane & 15, q = lane >> 4;
    int m0 = blockIdx.x * 32;

    bf16x8 ahi[2][NC], alo[2][NC];
#pragma unroll
    for (int t = 0; t < 2; ++t) {
        int row = m0 + t * 16 + l;
        if (row >= M) row = M - 1;  // clamp loads; stores guarded below
        const float* arow = A + (size_t)row * K + q * 8;
#pragma unroll
        for (int c = 0; c < NC; ++c) {
            float4 v0 = *(const float4*)(arow + c * 32);
            float4 v1 = *(const float4*)(arow + c * 32 + 4);
            float vv[8] = {v0.x, v0.y, v0.z, v0.w, v1.x, v1.y, v1.z, v1.w};
#pragma unroll
            for (int j = 0; j < 8; ++j) {
                unsigned short hb = bf16_rne(vv[j]);
                float hf = __uint_as_float((unsigned)hb << 16);
                ahi[t][c][j] = (short)hb;
                alo[t][c][j] = (short)bf16_rne(vv[j] - hf);
            }
        }
    }

    float ps[2][4] = {}, pd[2][4] = {};
    const size_t brow = (size_t)l * K + q * 8;
#pragma unroll 2
    for (int n = 0; n < 16; ++n) {
        const unsigned short* bh = Bhi + (size_t)(n * 16) * K + brow;
        const unsigned short* bl = Blo + (size_t)(n * 16) * K + brow;
        bf16x8 bhf[NC], blf[NC];
#pragma unroll
        for (int c = 0; c < NC; ++c) {
            bhf[c] = *(const bf16x8*)(bh + c * 32);
            blf[c] = *(const bf16x8*)(bl + c * 32);
        }
        f32x4 acc0 = {0.f, 0.f, 0.f, 0.f}, acc1 = {0.f, 0.f, 0.f, 0.f};
#pragma unroll
        for (int c = 0; c < NC; ++c) {
            acc0 = __builtin_amdgcn_mfma_f32_16x16x32_bf16(ahi[0][c], bhf[c], acc0, 0, 0, 0);
            acc1 = __builtin_amdgcn_mfma_f32_16x16x32_bf16(ahi[1][c], bhf[c], acc1, 0, 0, 0);
            acc0 = __builtin_amdgcn_mfma_f32_16x16x32_bf16(ahi[0][c], blf[c], acc0, 0, 0, 0);
            acc1 = __builtin_amdgcn_mfma_f32_16x16x32_bf16(ahi[1][c], blf[c], acc1, 0, 0, 0);
            acc0 = __builtin_amdgcn_mfma_f32_16x16x32_bf16(alo[0][c], bhf[c], acc0, 0, 0, 0);
            acc1 = __builtin_amdgcn_mfma_f32_16x16x32_bf16(alo[1][c], bhf[c], acc1, 0, 0, 0);
        }
        float av = aperm[n * 16 + l], dv = adperm[n * 16 + l];
        // panel-major C address: col j=n*16+l -> slab n>>1, word (n&1)*16+l
        size_t pb = (size_t)(n >> 1) * ((size_t)NN * 32) + (size_t)(n & 1) * 16 + l;
#pragma unroll
        for (int r = 0; r < 4; ++r) {
            ps[0][r] += acc0[r] * av; pd[0][r] += acc0[r] * dv;
            ps[1][r] += acc1[r] * av; pd[1][r] += acc1[r] * dv;
            int gm0 = m0 + q * 4 + r;
            if (gm0 < M) C16[pb + (size_t)gm0 * 32] = __float2half(acc0[r]);
            int gm1 = m0 + 16 + q * 4 + r;
            if (gm1 < M) C16[pb + (size_t)gm1 * 32] = __float2half(acc1[r]);
        }
    }
#pragma unroll
    for (int t = 0; t < 2; ++t)
#pragma unroll
        for (int r = 0; r < 4; ++r) {
            ps[t][r] += __shfl_xor(ps[t][r], 4);
            ps[t][r] += __shfl_xor(ps[t][r], 8);
            pd[t][r] += __shfl_xor(pd[t][r], 4);
            pd[t][r] += __shfl_xor(pd[t][r], 8);
        }
    if (l < 4) {
#pragma unroll
        for (int t = 0; t < 2; ++t)
#pragma unroll
            for (int r = 0; r < 4; ++r) {
                int gm = m0 + t * 16 + q * 4 + r;
                if (gm < M) {
                    os[(size_t)gm * 4 + l] = ps[t][r];
                    od[(size_t)gm * 4 + l] = pd[t][r];
                }
            }
    }
}

__device__ __forceinline__ float lrelu_exp(float x) {
    x = x > 0.f ? x : 0.2f * x;
    return __expf(x);
}

// Edge-softmax precompute: wave per dst, lane per edge. Gathers as_[s]
// (800 KB, L2-resident), computes u=exp(lrelu(.)), reduces denom, writes
// NORMALIZED fp16 alpha[E][4] (already scaled by 0.25 head-mean).
__global__ __launch_bounds__(256) void k_alpha(const int* __restrict__ rowptr,
                                               const int* __restrict__ csr_src,
                                               const float* __restrict__ as_,
                                               const float* __restrict__ ad_,
                                               __half* __restrict__ alpha16) {
    int w = threadIdx.x >> 6;
    int lane = threadIdx.x & 63;
    int d = blockIdx.x * 4 + w;
    if (d >= NN) return;
    int beg = rowptr[d], end = rowptr[d + 1];
    float4 adv = *(const float4*)(ad_ + d * 4);
    float4 u0 = make_float4(0.f, 0.f, 0.f, 0.f);
    float4 den = make_float4(0.f, 0.f, 0.f, 0.f);
    int i0 = beg + lane;
    if (i0 < end) {
        int s = csr_src[i0];
        float4 sv = *(const float4*)(as_ + s * 4);
        u0.x = lrelu_exp(sv.x + adv.x);
        u0.y = lrelu_exp(sv.y + adv.y);
        u0.z = lrelu_exp(sv.z + adv.z);
        u0.w = lrelu_exp(sv.w + adv.w);
        den = u0;
    }
    for (int i = i0 + 64; i < end; i += 64) {
        int s = csr_src[i];
        float4 sv = *(const float4*)(as_ + s * 4);
        float4 u;
        u.x = lrelu_exp(sv.x + adv.x);
        u.y = lrelu_exp(sv.y + adv.y);
        u.z = lrelu_exp(sv.z + adv.z);
        u.w = lrelu_exp(sv.w + adv.w);
        __half2 q0 = __floats2half2_rn(fminf(u.x, 60000.f), fminf(u.y, 60000.f));
        __half2 q1 = __floats2half2_rn(fminf(u.z, 60000.f), fminf(u.w, 60000.f));
        *(uint2*)(alpha16 + (size_t)i * 4) = make_uint2(*(unsigned*)&q0, *(unsigned*)&q1);
        den.x += u.x; den.y += u.y; den.z += u.z; den.w += u.w;
    }
#pragma unroll
    for (int off = 32; off > 0; off >>= 1) {
        den.x += __shfl_xor(den.x, off);
        den.y += __shfl_xor(den.y, off);
        den.z += __shfl_xor(den.z, off);
        den.w += __shfl_xor(den.w, off);
    }
    float4 dinv = make_float4(0.25f / den.x, 0.25f / den.y,
                              0.25f / den.z, 0.25f / den.w);
    if (i0 < end) {
        __half2 q0 = __floats2half2_rn(u0.x * dinv.x, u0.y * dinv.y);
        __half2 q1 = __floats2half2_rn(u0.z * dinv.z, u0.w * dinv.w);
        *(uint2*)(alpha16 + (size_t)i0 * 4) = make_uint2(*(unsigned*)&q0, *(unsigned*)&q1);
    }
    for (int i = i0 + 64; i < end; i += 64) {
        uint2 r = *(const uint2*)(alpha16 + (size_t)i * 4);
        float2 fa = __half22float2(*(const __half2*)&r.x);
        float2 fb = __half22float2(*(const __half2*)&r.y);
        __half2 q0 = __floats2half2_rn(fa.x * dinv.x, fa.y * dinv.y);
        __half2 q1 = __floats2half2_rn(fb.x * dinv.z, fb.y * dinv.w);
        *(uint2*)(alpha16 + (size_t)i * 4) = make_uint2(*(unsigned*)&q0, *(unsigned*)&q1);
    }
}

// Persistent XCD-affine panel aggregation, v3 (latency-chain fix of r3):
// r3 was latency-bound (285us, VALUBusy 20%, FETCH traffic says ~25us):
// each inner iteration carried a csr(HBM ~900cy) -> hv(L2 ~200cy) CHAINED
// load pair that a 1-deep double-buffer cannot split. v3 bulk-stages the
// claim's CONTIGUOUS csr+alpha edge range into wave-private LDS (coalesced,
// 8 loads in flight, double-buffered across CH=256-edge chunks), so phase B
// has a single-level, independent-iteration hv gather -- arbitrarily deep
// MLP, no chain. rowptr[d0..d0+32] lives in one lane-register via shfl.
// No __syncthreads (LDS buffers are wave-private; same-wave ds order is HW-
// guaranteed). Claim/affinity machinery identical to r3 (FETCH-optimal).
__global__ __launch_bounds__(256) void k_aggr_xcd(
        const int* __restrict__ rowptr, const int* __restrict__ csr_src,
        const __half* __restrict__ alpha16, const __half* __restrict__ hp,
        const float* __restrict__ bias, float* __restrict__ out,
        int* __restrict__ cur) {
    __shared__ int ssrc[4][2][CH];
    __shared__ uint2 salp[4][2][CH];
    unsigned xcc;
    asm volatile("s_getreg_b32 %0, hwreg(HW_REG_XCC_ID)" : "=s"(xcc));
    int p0 = (int)(xcc & 7u);
    int w = threadIdx.x >> 6;
    int lane = threadIdx.x & 63;
    int e8 = lane >> 3, dim8 = lane & 7;
    for (int pp = 0; pp < 8; ++pp) {
        int p = (p0 + pp) & 7;
        if (pp && *(volatile int*)&cur[p * 16] >= NU) continue;
        const __half* hsl = hp + (size_t)p * ((size_t)NN * 32) + dim8 * 4;
        float bv = bias[p * 8 + dim8];
        for (;;) {
            int t = 0;
            if (lane == 0) t = atomicAdd(&cur[p * 16], 1);
            t = __shfl(t, 0);
            if (t >= NU) break;
            int d0 = t * 32, d1 = d0 + 32;
            if (d1 > NN) d1 = NN;
            int rp = 0;
            if (lane <= d1 - d0) rp = rowptr[d0 + lane];
            int ebeg = __shfl(rp, 0);
            int eend = __shfl(rp, d1 - d0);
            // stage chunk 0 (self-loops guarantee eend > ebeg)
            {
                int c0s[CH / 64]; uint2 c0a[CH / 64];
#pragma unroll
                for (int it = 0; it < CH / 64; ++it) {
                    int j = ebeg + it * 64 + lane;
                    if (j >= eend) j = eend - 1;
                    c0s[it] = csr_src[j];
                    c0a[it] = *(const uint2*)(alpha16 + (size_t)j * 4);
                }
#pragma unroll
                for (int it = 0; it < CH / 64; ++it) {
                    ssrc[w][0][it * 64 + lane] = c0s[it];
                    salp[w][0][it * 64 + lane] = c0a[it];
                }
            }
            int d = d0;
            float acc = 0.f;
            int nch = (eend - ebeg + CH - 1) / CH;
            for (int c = 0; c < nch; ++c) {
                int cbeg = ebeg + c * CH;
                int cend = cbeg + CH;
                if (cend > eend) cend = eend;
                int buf = c & 1;
                int nbeg = cbeg + CH;
                bool havenext = nbeg < eend;
                int pfs[CH / 64]; uint2 pfa[CH / 64];
                if (havenext) {  // issue next chunk's coalesced loads now
#pragma unroll
                    for (int it = 0; it < CH / 64; ++it) {
                        int j = nbeg + it * 64 + lane;
                        if (j >= eend) j = eend - 1;
                        pfs[it] = csr_src[j];
                        pfa[it] = *(const uint2*)(alpha16 + (size_t)j * 4);
                    }
                }
                const int* ssb = ssrc[w][buf];
                const uint2* sab = salp[w][buf];
                while (d < d1) {
                    int db = __shfl(rp, d - d0);
                    int de = __shfl(rp, d - d0 + 1);
                    int sb = db > cbeg ? db : cbeg;
                    int se = de < cend ? de : cend;
                    for (int j = sb + e8; j < se; j += 8) {
                        int li = j - cbeg;
                        int s = ssb[li];
                        uint2 a2 = sab[li];
                        uint2 hv = *(const uint2*)(hsl + (size_t)s * 32);
                        acc = __builtin_amdgcn_fdot2(as_h2(hv.x), as_h2(a2.x), acc, false);
                        acc = __builtin_amdgcn_fdot2(as_h2(hv.y), as_h2(a2.y), acc, false);
                    }
                    if (de <= cend) {  // dst complete in this chunk
                        acc += __shfl_xor(acc, 8);
                        acc += __shfl_xor(acc, 16);
                        acc += __shfl_xor(acc, 32);
                        if (e8 == 0) {
                            float v = acc + bv;
                            out[(size_t)d * 64 + p * 8 + dim8] = v > 0.f ? v : 0.f;
                        }
                        acc = 0.f;
                        ++d;
                    } else {
                        break;  // dst spans into next chunk; acc carries
                    }
                }
                if (havenext) {  // land prefetch into the other buffer
#pragma unroll
                    for (int it = 0; it < CH / 64; ++it) {
                        ssrc[w][buf ^ 1][it * 64 + lane] = pfs[it];
                        salp[w][buf ^ 1][it * 64 + lane] = pfa[it];
                    }
                }
            }
        }
    }
}

// batch is SORTED: binary-search per graph; 4 waves split the node loop.
__global__ __launch_bounds__(256) void k_pool_fc(const float* __restrict__ x3,
                                                 const int* __restrict__ batch,
                                                 const int* __restrict__ ei,
                                                 const float* __restrict__ fcW,
                                                 const float* __restrict__ fcb,
                                                 float* __restrict__ out) {
    __shared__ int sflag;
    int tid = threadIdx.x, lane = tid & 63, w = tid >> 6;
    int st = detect_stride(ei, tid, &sflag);
    int g = blockIdx.x;
    int lo = 0, hi = NN;
    while (lo < hi) { int mid = (lo + hi) >> 1; if (batch[(size_t)st * mid] < g) lo = mid + 1; else hi = mid; }
    int start = lo;
    hi = NN;
    while (lo < hi) { int mid = (lo + hi) >> 1; if (batch[(size_t)st * mid] < g + 1) lo = mid + 1; else hi = mid; }
    int end = lo;
    float sum = 0.f;
    for (int n = start + w; n < end; n += 4) sum += x3[n * 64 + lane];
    __shared__ float ls[4][64];
    ls[w][lane] = sum;
    __syncthreads();
    if (w == 0) {
        float c = (float)(end - start);
        if (c < 1.f) c = 1.f;
        float p = (ls[0][lane] + ls[1][lane] + ls[2][lane] + ls[3][lane]) / c;
#pragma unroll
        for (int o = 0; o < 16; ++o) {
            float v = p * fcW[lane * 16 + o];
#pragma unroll
            for (int off = 32; off > 0; off >>= 1) v += __shfl_down(v, off);
            if (lane == 0) out[g * 16 + o] = v + fcb[o];
        }
    }
}

extern "C" void kernel_launch(void* const* d_in, const int* in_sizes, int n_in,
                              void* d_out, int out_size, void* d_ws, size_t ws_size,
                              hipStream_t stream) {
    const float* x   = (const float*)d_in[0];
    const int*   ei  = (const int*)d_in[1];
    const int*   bat = (const int*)d_in[2];
    const float* W1  = (const float*)d_in[3];
    const float* a1s = (const float*)d_in[4];
    const float* a1d = (const float*)d_in[5];
    const float* b1  = (const float*)d_in[6];
    const float* W2  = (const float*)d_in[7];
    const float* a2s = (const float*)d_in[8];
    const float* a2d = (const float*)d_in[9];
    const float* b2  = (const float*)d_in[10];
    const float* fcW = (const float*)d_in[11];
    const float* fcb = (const float*)d_in[12];
    float* out = (float*)d_out;

    float* ws = (float*)d_ws;
    __half* h16  = (__half*)(ws + 256);           // [8][N][32] fp16 panel slabs
    float* as_   = (float*)(h16 + (size_t)NN * 256);  // [N,4]
    float* ad_   = as_ + NN * 4;                  // [N,4]
    float* xacc  = ad_ + NN * 4;                  // [N,64]
    int* src32   = (int*)(xacc + (size_t)NN * 64);// [E]
    int* dst32   = src32 + ETOT;                  // [E]
    int* deg     = dst32 + ETOT;                  // [N]
    int* rowptr  = deg + NN;                      // [N+1]
    int* cursor  = rowptr + NN + 1;               // [N]
    int* csr_src = cursor + NN;                   // [E]
    int* bsum    = csr_src + ETOT;                // [NBLK]
    char* p = (char*)(bsum + NBLK);
    p = (char*)(((size_t)p + 255) & ~(size_t)255);
    unsigned short* bt1h = (unsigned short*)p; p += 256 * 128 * 2;
    unsigned short* bt1l = (unsigned short*)p; p += 256 * 128 * 2;
    unsigned short* bt2h = (unsigned short*)p; p += 256 * 64 * 2;
    unsigned short* bt2l = (unsigned short*)p; p += 256 * 64 * 2;
    float* ap1  = (float*)p; p += 256 * 4;
    float* adp1 = (float*)p; p += 256 * 4;
    float* ap2  = (float*)p; p += 256 * 4;
    float* adp2 = (float*)p; p += 256 * 4;
    p = (char*)(((size_t)p + 255) & ~(size_t)255);
    __half* alpha16 = (__half*)p; p += (size_t)ETOT * 4 * 2;  // [E][4] fp16
    p = (char*)(((size_t)p + 255) & ~(size_t)255);
    int* curs = (int*)p; p += 256 * 4;  // 8 cursors x 64B pad x 2 layers

    const int wb = (NN + 3) / 4;  // 12500 wave-per-node blocks (k_alpha)

    // ---- one-time per call: indices + dst-CSR + weight planes ----
    hipMemsetAsync(deg, 0, NN * sizeof(int), stream);
    hipMemsetAsync(curs, 0, 256 * sizeof(int), stream);
    k_prep<<<EB + 192, 256, 0, stream>>>(ei, src32, dst32, deg,
                                         W1, a1s, a1d, W2, a2s, a2d,
                                         bt1h, bt1l, bt2h, bt2l,
                                         ap1, adp1, ap2, adp2);
    k_blocksum<<<NBLK, 256, 0, stream>>>(deg, bsum);
    k_scan_final<<<NBLK, 256, 0, stream>>>(deg, bsum, rowptr, cursor);
    k_scatter<<<EB, 256, 0, stream>>>(src32, dst32, cursor, csr_src);

    const int gg = (NN + 31) / 32;  // 1563 single-wave blocks, 32 rows each
    // ---- layer 1 ----
    k_gemm_mfma<128><<<gg, 64, 0, stream>>>(x, bt1h, bt1l, ap1, adp1, h16, as_, ad_, NN);
    k_alpha<<<wb, 256, 0, stream>>>(rowptr, csr_src, as_, ad_, alpha16);
    k_aggr_xcd<<<2048, 256, 0, stream>>>(rowptr, csr_src, alpha16, h16, b1, xacc, curs);
    // ---- layer 2 ----
    k_gemm_mfma<64><<<gg, 64, 0, stream>>>(xacc, bt2h, bt2l, ap2, adp2, h16, as_, ad_, NN);
    k_alpha<<<wb, 256, 0, stream>>>(rowptr, csr_src, as_, ad_, alpha16);
    k_aggr_xcd<<<2048, 256, 0, stream>>>(rowptr, csr_src, alpha16, h16, b2, xacc, curs + 128);
    // ---- pool + fc ----
    k_pool_fc<<<NG, 256, 0, stream>>>(xacc, bat, ei, fcW, fcb, out);
}

// Round 5
// 381.615 us; speedup vs baseline: 2.6550x; 2.1509x over previous
//
#include <hip/hip_runtime.h>
#include <hip/hip_bf16.h>
#include <hip/hip_fp16.h>

#define NN 50000
#define EE 800000
#define ETOT 850000
#define NG 500
#define NBLK ((NN + 255) / 256)  // 196
#define EB ((ETOT + 255) / 256)  // 3321

typedef __attribute__((ext_vector_type(8))) short bf16x8;
typedef __attribute__((ext_vector_type(4))) float f32x4;
typedef _Float16 h2f __attribute__((ext_vector_type(2)));

__device__ __forceinline__ h2f as_h2(unsigned u) {
    union { unsigned u; h2f h; } x;
    x.u = u;
    return x.h;
}

__device__ __forceinline__ unsigned short bf16_rne(float v) {
    unsigned u = __float_as_uint(v);
    unsigned r = u + 0x7FFFu + ((u >> 16) & 1u);
    return (unsigned short)(r >> 16);
}

// Per-block int64/int32 detect: node ids < 50000 => int64 has all-odd-words 0.
__device__ __forceinline__ int detect_stride(const int* __restrict__ ei,
                                             int tid, int* sflag) {
    if (tid < 64) {
        unsigned long long b = __ballot(ei[2 * tid + 1] != 0);
        if (tid == 0) *sflag = b ? 1 : 2;
    }
    __syncthreads();
    return *sflag;
}

// W [K][256] fp32 -> transposed, column-permuted bf16 hi/lo planes [256][K];
// permuted col j = dim*4+head. Also permuted a_src/a_dst.
__device__ __forceinline__ void prepw_one(const float* __restrict__ W,
                                          const float* __restrict__ asrc,
                                          const float* __restrict__ adst,
                                          unsigned short* __restrict__ bhi,
                                          unsigned short* __restrict__ blo,
                                          float* __restrict__ ap,
                                          float* __restrict__ adp,
                                          int K, int t) {
    int j = t / K, k = t - j * K;
    int d = j >> 2, h = j & 3;
    float v = W[k * 256 + h * 64 + d];
    unsigned short hb = bf16_rne(v);
    float hf = __uint_as_float((unsigned)hb << 16);
    bhi[t] = hb;
    blo[t] = bf16_rne(v - hf);
    if (k == 0) { ap[j] = asrc[h * 64 + d]; adp[j] = adst[h * 64 + d]; }
}

// Edge prep (int32 src/dst + self-loops + degree histogram) fused with
// both layers' weight prep in the tail blocks.
__global__ __launch_bounds__(256) void k_prep(
        const int* __restrict__ ei, int* __restrict__ src32,
        int* __restrict__ dst32, int* __restrict__ deg,
        const float* __restrict__ W1, const float* __restrict__ a1s,
        const float* __restrict__ a1d, const float* __restrict__ W2,
        const float* __restrict__ a2s, const float* __restrict__ a2d,
        unsigned short* __restrict__ b1h, unsigned short* __restrict__ b1l,
        unsigned short* __restrict__ b2h, unsigned short* __restrict__ b2l,
        float* __restrict__ ap1, float* __restrict__ adp1,
        float* __restrict__ ap2, float* __restrict__ adp2) {
    int blk = blockIdx.x;
    if (blk >= EB) {  // weight-prep tail
        int g = blk - EB;
        if (g < 128)
            prepw_one(W1, a1s, a1d, b1h, b1l, ap1, adp1, 128, g * 256 + threadIdx.x);
        else
            prepw_one(W2, a2s, a2d, b2h, b2l, ap2, adp2, 64, (g - 128) * 256 + threadIdx.x);
        return;
    }
    __shared__ int sflag;
    int tid = threadIdx.x;
    int st = detect_stride(ei, tid, &sflag);
    int e = blk * 256 + tid;
    if (e >= ETOT) return;
    int s, d;
    if (e < EE) {
        s = ei[(size_t)st * e];
        d = ei[(size_t)st * (EE + e)];
    } else {
        s = d = e - EE;  // self-loop
    }
    src32[e] = s;
    dst32[e] = d;
    atomicAdd(&deg[d], 1);
}

__global__ __launch_bounds__(256) void k_blocksum(const int* __restrict__ deg,
                                                  int* __restrict__ bsum) {
    __shared__ int l[256];
    int gid = blockIdx.x * 256 + threadIdx.x;
    int tid = threadIdx.x;
    l[tid] = (gid < NN) ? deg[gid] : 0;
    __syncthreads();
    for (int o = 128; o > 0; o >>= 1) {
        if (tid < o) l[tid] += l[tid + o];
        __syncthreads();
    }
    if (tid == 0) bsum[blockIdx.x] = l[0];
}

// Each block re-scans bsum[196] locally, then scans its 256-chunk of deg.
__global__ __launch_bounds__(256) void k_scan_final(const int* __restrict__ deg,
                                                    const int* __restrict__ bsum,
                                                    int* __restrict__ rowptr,
                                                    int* __restrict__ cursor) {
    __shared__ int lb[256];
    __shared__ int l[256];
    int tid = threadIdx.x;
    int vb = (tid < NBLK) ? bsum[tid] : 0;
    lb[tid] = vb;
    __syncthreads();
    for (int d = 1; d < 256; d <<= 1) {
        int t = (tid >= d) ? lb[tid - d] : 0;
        __syncthreads();
        lb[tid] += t;
        __syncthreads();
    }
    int boffb = lb[blockIdx.x] - bsum[blockIdx.x];
    int gid = blockIdx.x * 256 + tid;
    int v = (gid < NN) ? deg[gid] : 0;
    l[tid] = v;
    __syncthreads();
    for (int d = 1; d < 256; d <<= 1) {
        int t = (tid >= d) ? l[tid - d] : 0;
        __syncthreads();
        l[tid] += t;
        __syncthreads();
    }
    int ex = l[tid] - v + boffb;
    if (gid < NN) { rowptr[gid] = ex; cursor[gid] = ex; }
    if (gid == 0) rowptr[NN] = ETOT;
}

__global__ __launch_bounds__(256) void k_scatter(const int* __restrict__ src32,
                                                 const int* __restrict__ dst32,
                                                 int* __restrict__ cursor,
                                                 int* __restrict__ csr_src) {
    int e = blockIdx.x * 256 + threadIdx.x;
    if (e >= ETOT) return;
    int pos = atomicAdd(&cursor[dst32[e]], 1);
    csr_src[pos] = src32[e];
}

// C[M,256] = A[M,K] @ B[K,256] via MFMA 16x16x32 bf16-split (fp32-grade).
// Wave = 32 rows x 16 n-tiles: measured-best config (r12). n-split (r14),
// B-prefetch (r15), and C^T (r16) all regressed -- this shape maximizes
// per-wave B reuse at the occupancy this tiny GEMM can sustain.
template <int K>
__global__ __launch_bounds__(64) void k_gemm_mfma(
        const float* __restrict__ A,
        const unsigned short* __restrict__ Bhi,
        const unsigned short* __restrict__ Blo,
        const float* __restrict__ aperm,
        const float* __restrict__ adperm,
        __half* __restrict__ C16,
        float* __restrict__ os,
        float* __restrict__ od, int M) {
    const int NC = K / 32;
    int lane = threadIdx.x;
    int l = lane & 15, q = lane >> 4;
    int m0 = blockIdx.x * 32;

    bf16x8 ahi[2][NC], alo[2][NC];
#pragma unroll
    for (int t = 0; t < 2; ++t) {
        int row = m0 + t * 16 + l;
        if (row >= M) row = M - 1;  // clamp loads; stores guarded below
        const float* arow = A + (size_t)row * K + q * 8;
#pragma unroll
        for (int c = 0; c < NC; ++c) {
            float4 v0 = *(const float4*)(arow + c * 32);
            float4 v1 = *(const float4*)(arow + c * 32 + 4);
            float vv[8] = {v0.x, v0.y, v0.z, v0.w, v1.x, v1.y, v1.z, v1.w};
#pragma unroll
            for (int j = 0; j < 8; ++j) {
                unsigned short hb = bf16_rne(vv[j]);
                float hf = __uint_as_float((unsigned)hb << 16);
                ahi[t][c][j] = (short)hb;
                alo[t][c][j] = (short)bf16_rne(vv[j] - hf);
            }
        }
    }

    float ps[2][4] = {}, pd[2][4] = {};
    const size_t brow = (size_t)l * K + q * 8;
#pragma unroll 2
    for (int n = 0; n < 16; ++n) {
        const unsigned short* bh = Bhi + (size_t)(n * 16) * K + brow;
        const unsigned short* bl = Blo + (size_t)(n * 16) * K + brow;
        bf16x8 bhf[NC], blf[NC];
#pragma unroll
        for (int c = 0; c < NC; ++c) {
            bhf[c] = *(const bf16x8*)(bh + c * 32);
            blf[c] = *(const bf16x8*)(bl + c * 32);
        }
        f32x4 acc0 = {0.f, 0.f, 0.f, 0.f}, acc1 = {0.f, 0.f, 0.f, 0.f};
#pragma unroll
        for (int c = 0; c < NC; ++c) {
            acc0 = __builtin_amdgcn_mfma_f32_16x16x32_bf16(ahi[0][c], bhf[c], acc0, 0, 0, 0);
            acc1 = __builtin_amdgcn_mfma_f32_16x16x32_bf16(ahi[1][c], bhf[c], acc1, 0, 0, 0);
            acc0 = __builtin_amdgcn_mfma_f32_16x16x32_bf16(ahi[0][c], blf[c], acc0, 0, 0, 0);
            acc1 = __builtin_amdgcn_mfma_f32_16x16x32_bf16(ahi[1][c], blf[c], acc1, 0, 0, 0);
            acc0 = __builtin_amdgcn_mfma_f32_16x16x32_bf16(alo[0][c], bhf[c], acc0, 0, 0, 0);
            acc1 = __builtin_amdgcn_mfma_f32_16x16x32_bf16(alo[1][c], bhf[c], acc1, 0, 0, 0);
        }
        float av = aperm[n * 16 + l], dv = adperm[n * 16 + l];
#pragma unroll
        for (int r = 0; r < 4; ++r) {
            ps[0][r] += acc0[r] * av; pd[0][r] += acc0[r] * dv;
            ps[1][r] += acc1[r] * av; pd[1][r] += acc1[r] * dv;
            int gm0 = m0 + q * 4 + r;
            if (gm0 < M) C16[(size_t)gm0 * 256 + n * 16 + l] = __float2half(acc0[r]);
            int gm1 = m0 + 16 + q * 4 + r;
            if (gm1 < M) C16[(size_t)gm1 * 256 + n * 16 + l] = __float2half(acc1[r]);
        }
    }
#pragma unroll
    for (int t = 0; t < 2; ++t)
#pragma unroll
        for (int r = 0; r < 4; ++r) {
            ps[t][r] += __shfl_xor(ps[t][r], 4);
            ps[t][r] += __shfl_xor(ps[t][r], 8);
            pd[t][r] += __shfl_xor(pd[t][r], 4);
            pd[t][r] += __shfl_xor(pd[t][r], 8);
        }
    if (l < 4) {
#pragma unroll
        for (int t = 0; t < 2; ++t)
#pragma unroll
            for (int r = 0; r < 4; ++r) {
                int gm = m0 + t * 16 + q * 4 + r;
                if (gm < M) {
                    os[(size_t)gm * 4 + l] = ps[t][r];
                    od[(size_t)gm * 4 + l] = pd[t][r];
                }
            }
    }
}

__device__ __forceinline__ float lrelu_exp(float x) {
    x = x > 0.f ? x : 0.2f * x;
    return __expf(x);
}

// Wave per dst node; lane=dim; ONE 8B gather/edge; fdot2 inner op; 4-deep
// pipeline; LDS-staged (s, fp16-alpha). At random-gather fill-path roofline:
// FETCH pinned at 206 MB / ~3.55 TB/s across 5 issue-side variants.
__global__ __launch_bounds__(256) void k_aggr(const int* __restrict__ rowptr,
                                              const int* __restrict__ csr_src,
                                              const float* __restrict__ as_,
                                              const float* __restrict__ ad_,
                                              const __half* __restrict__ h16,
                                              const float* __restrict__ bias,
                                              float* __restrict__ out) {
    __shared__ uint2 als16[4][64];
    __shared__ int sss[4][64];
    int w = threadIdx.x >> 6;
    int lane = threadIdx.x & 63;
    int d = blockIdx.x * 4 + w;
    if (d >= NN) return;
    int beg = rowptr[d], end = rowptr[d + 1];
    float4 adv = *(const float4*)(ad_ + d * 4);

    int s0 = 0;
    float4 u0 = make_float4(0.f, 0.f, 0.f, 0.f);
    float4 den = make_float4(0.f, 0.f, 0.f, 0.f);
    int i0 = beg + lane;
    if (i0 < end) {
        s0 = csr_src[i0];
        float4 sv = *(const float4*)(as_ + s0 * 4);
        u0.x = lrelu_exp(sv.x + adv.x);
        u0.y = lrelu_exp(sv.y + adv.y);
        u0.z = lrelu_exp(sv.z + adv.z);
        u0.w = lrelu_exp(sv.w + adv.w);
        den = u0;
    }
    for (int i = i0 + 64; i < end; i += 64) {
        int s = csr_src[i];
        float4 sv = *(const float4*)(as_ + s * 4);
        den.x += lrelu_exp(sv.x + adv.x);
        den.y += lrelu_exp(sv.y + adv.y);
        den.z += lrelu_exp(sv.z + adv.z);
        den.w += lrelu_exp(sv.w + adv.w);
    }
#pragma unroll
    for (int off = 32; off > 0; off >>= 1) {
        den.x += __shfl_xor(den.x, off);
        den.y += __shfl_xor(den.y, off);
        den.z += __shfl_xor(den.z, off);
        den.w += __shfl_xor(den.w, off);
    }
    float4 dinv = make_float4(0.25f / den.x, 0.25f / den.y,
                              0.25f / den.z, 0.25f / den.w);
    {
        __half2 q0 = __floats2half2_rn(u0.x * dinv.x, u0.y * dinv.y);
        __half2 q1 = __floats2half2_rn(u0.z * dinv.z, u0.w * dinv.w);
        als16[w][lane] = make_uint2(*(unsigned*)&q0, *(unsigned*)&q1);
        sss[w][lane] = s0;
    }

    int cnt = end - beg;
    if (cnt > 64) cnt = 64;
    int cnt4 = (cnt + 3) & ~3;
    float acc = 0.f;
    int4 sq = *(const int4*)&sss[w][0];
    uint2 r0 = *(const uint2*)(h16 + (size_t)sq.x * 256 + lane * 4);
    uint2 r1 = *(const uint2*)(h16 + (size_t)sq.y * 256 + lane * 4);
    uint2 r2 = *(const uint2*)(h16 + (size_t)sq.z * 256 + lane * 4);
    uint2 r3 = *(const uint2*)(h16 + (size_t)sq.w * 256 + lane * 4);
    for (int j = 0; j < cnt4; j += 4) {
        int jn = (j + 4) & 63;
        int4 sn = *(const int4*)&sss[w][jn];
        uint2 n0 = *(const uint2*)(h16 + (size_t)sn.x * 256 + lane * 4);
        uint2 n1 = *(const uint2*)(h16 + (size_t)sn.y * 256 + lane * 4);
        uint2 n2 = *(const uint2*)(h16 + (size_t)sn.z * 256 + lane * 4);
        uint2 n3 = *(const uint2*)(h16 + (size_t)sn.w * 256 + lane * 4);
        uint4 A01 = *(const uint4*)&als16[w][j];
        uint4 A23 = *(const uint4*)&als16[w][j + 2];
        acc = __builtin_amdgcn_fdot2(as_h2(r0.x), as_h2(A01.x), acc, false);
        acc = __builtin_amdgcn_fdot2(as_h2(r0.y), as_h2(A01.y), acc, false);
        acc = __builtin_amdgcn_fdot2(as_h2(r1.x), as_h2(A01.z), acc, false);
        acc = __builtin_amdgcn_fdot2(as_h2(r1.y), as_h2(A01.w), acc, false);
        acc = __builtin_amdgcn_fdot2(as_h2(r2.x), as_h2(A23.x), acc, false);
        acc = __builtin_amdgcn_fdot2(as_h2(r2.y), as_h2(A23.y), acc, false);
        acc = __builtin_amdgcn_fdot2(as_h2(r3.x), as_h2(A23.z), acc, false);
        acc = __builtin_amdgcn_fdot2(as_h2(r3.y), as_h2(A23.w), acc, false);
        r0 = n0; r1 = n1; r2 = n2; r3 = n3;
    }
    for (int chunk = beg + 64; chunk < end; chunk += 64) {
        int i = chunk + lane;
        int s = 0;
        float4 al = make_float4(0.f, 0.f, 0.f, 0.f);
        if (i < end) {
            s = csr_src[i];
            float4 sv = *(const float4*)(as_ + s * 4);
            al.x = lrelu_exp(sv.x + adv.x) * dinv.x;
            al.y = lrelu_exp(sv.y + adv.y) * dinv.y;
            al.z = lrelu_exp(sv.z + adv.z) * dinv.z;
            al.w = lrelu_exp(sv.w + adv.w) * dinv.w;
        }
        int cc = end - chunk;
        if (cc > 64) cc = 64;
        for (int j = 0; j < cc; ++j) {
            int sj = __shfl(s, j);
            float a0 = __shfl(al.x, j), a1 = __shfl(al.y, j);
            float a2 = __shfl(al.z, j), a3 = __shfl(al.w, j);
            uint2 raw = *(const uint2*)(h16 + (size_t)sj * 256 + lane * 4);
            float2 fa = __half22float2(*(const __half2*)&raw.x);
            float2 fb = __half22float2(*(const __half2*)&raw.y);
            acc += a0 * fa.x + a1 * fa.y + a2 * fb.x + a3 * fb.y;
        }
    }
    float v = acc + bias[lane];
    out[d * 64 + lane] = v > 0.f ? v : 0.f;
}

// batch is SORTED: binary-search per graph; 4 waves split the node loop.
__global__ __launch_bounds__(256) void k_pool_fc(const float* __restrict__ x3,
                                                 const int* __restrict__ batch,
                                                 const int* __restrict__ ei,
                                                 const float* __restrict__ fcW,
                                                 const float* __restrict__ fcb,
                                                 float* __restrict__ out) {
    __shared__ int sflag;
    int tid = threadIdx.x, lane = tid & 63, w = tid >> 6;
    int st = detect_stride(ei, tid, &sflag);
    int g = blockIdx.x;
    int lo = 0, hi = NN;
    while (lo < hi) { int mid = (lo + hi) >> 1; if (batch[(size_t)st * mid] < g) lo = mid + 1; else hi = mid; }
    int start = lo;
    hi = NN;
    while (lo < hi) { int mid = (lo + hi) >> 1; if (batch[(size_t)st * mid] < g + 1) lo = mid + 1; else hi = mid; }
    int end = lo;
    float sum = 0.f;
    for (int n = start + w; n < end; n += 4) sum += x3[n * 64 + lane];
    __shared__ float ls[4][64];
    ls[w][lane] = sum;
    __syncthreads();
    if (w == 0) {
        float c = (float)(end - start);
        if (c < 1.f) c = 1.f;
        float p = (ls[0][lane] + ls[1][lane] + ls[2][lane] + ls[3][lane]) / c;
#pragma unroll
        for (int o = 0; o < 16; ++o) {
            float v = p * fcW[lane * 16 + o];
#pragma unroll
            for (int off = 32; off > 0; off >>= 1) v += __shfl_down(v, off);
            if (lane == 0) out[g * 16 + o] = v + fcb[o];
        }
    }
}

extern "C" void kernel_launch(void* const* d_in, const int* in_sizes, int n_in,
                              void* d_out, int out_size, void* d_ws, size_t ws_size,
                              hipStream_t stream) {
    const float* x   = (const float*)d_in[0];
    const int*   ei  = (const int*)d_in[1];
    const int*   bat = (const int*)d_in[2];
    const float* W1  = (const float*)d_in[3];
    const float* a1s = (const float*)d_in[4];
    const float* a1d = (const float*)d_in[5];
    const float* b1  = (const float*)d_in[6];
    const float* W2  = (const float*)d_in[7];
    const float* a2s = (const float*)d_in[8];
    const float* a2d = (const float*)d_in[9];
    const float* b2  = (const float*)d_in[10];
    const float* fcW = (const float*)d_in[11];
    const float* fcb = (const float*)d_in[12];
    float* out = (float*)d_out;

    float* ws = (float*)d_ws;
    __half* h16  = (__half*)(ws + 256);           // [N,256] fp16 [n][dim][head]
    float* as_   = (float*)(h16 + (size_t)NN * 256);  // [N,4]
    float* ad_   = as_ + NN * 4;                  // [N,4]
    float* xacc  = ad_ + NN * 4;                  // [N,64]
    int* src32   = (int*)(xacc + (size_t)NN * 64);// [E]
    int* dst32   = src32 + ETOT;                  // [E]
    int* deg     = dst32 + ETOT;                  // [N]
    int* rowptr  = deg + NN;                      // [N+1]
    int* cursor  = rowptr + NN + 1;               // [N]
    int* csr_src = cursor + NN;                   // [E]
    int* bsum    = csr_src + ETOT;                // [NBLK]
    char* p = (char*)(bsum + NBLK);
    p = (char*)(((size_t)p + 255) & ~(size_t)255);
    unsigned short* bt1h = (unsigned short*)p; p += 256 * 128 * 2;
    unsigned short* bt1l = (unsigned short*)p; p += 256 * 128 * 2;
    unsigned short* bt2h = (unsigned short*)p; p += 256 * 64 * 2;
    unsigned short* bt2l = (unsigned short*)p; p += 256 * 64 * 2;
    float* ap1  = (float*)p; p += 256 * 4;
    float* adp1 = (float*)p; p += 256 * 4;
    float* ap2  = (float*)p; p += 256 * 4;
    float* adp2 = (float*)p; p += 256 * 4;

    const int wb = (NN * 64 + 255) / 256;  // 12500 wave-per-node blocks

    // ---- one-time per call: indices + dst-CSR + weight planes ----
    hipMemsetAsync(deg, 0, NN * sizeof(int), stream);
    k_prep<<<EB + 192, 256, 0, stream>>>(ei, src32, dst32, deg,
                                         W1, a1s, a1d, W2, a2s, a2d,
                                         bt1h, bt1l, bt2h, bt2l,
                                         ap1, adp1, ap2, adp2);
    k_blocksum<<<NBLK, 256, 0, stream>>>(deg, bsum);
    k_scan_final<<<NBLK, 256, 0, stream>>>(deg, bsum, rowptr, cursor);
    k_scatter<<<EB, 256, 0, stream>>>(src32, dst32, cursor, csr_src);

    const int gg = (NN + 31) / 32;  // 1563 single-wave blocks, 32 rows each
    // ---- layer 1 ----
    k_gemm_mfma<128><<<gg, 64, 0, stream>>>(x, bt1h, bt1l, ap1, adp1, h16, as_, ad_, NN);
    k_aggr<<<wb, 256, 0, stream>>>(rowptr, csr_src, as_, ad_, h16, b1, xacc);
    // ---- layer 2 ----
    k_gemm_mfma<64><<<gg, 64, 0, stream>>>(xacc, bt2h, bt2l, ap2, adp2, h16, as_, ad_, NN);
    k_aggr<<<wb, 256, 0, stream>>>(rowptr, csr_src, as_, ad_, h16, b2, xacc);
    // ---- pool + fc ----
    k_pool_fc<<<NG, 256, 0, stream>>>(xacc, bat, ei, fcW, fcb, out);
}

// Round 6
// 377.029 us; speedup vs baseline: 2.6873x; 1.0122x over previous
//
#include <hip/hip_runtime.h>
#include <hip/hip_bf16.h>
#include <hip/hip_fp16.h>

#define NN 50000
#define EE 800000
#define ETOT 850000
#define NG 500
#define NBLK ((NN + 255) / 256)  // 196
#define EB ((ETOT + 255) / 256)  // 3321
#define NCLS 16                  // atomic-privatization classes

typedef __attribute__((ext_vector_type(8))) short bf16x8;
typedef __attribute__((ext_vector_type(4))) float f32x4;
typedef _Float16 h2f __attribute__((ext_vector_type(2)));

__device__ __forceinline__ h2f as_h2(unsigned u) {
    union { unsigned u; h2f h; } x;
    x.u = u;
    return x.h;
}

__device__ __forceinline__ unsigned short bf16_rne(float v) {
    unsigned u = __float_as_uint(v);
    unsigned r = u + 0x7FFFu + ((u >> 16) & 1u);
    return (unsigned short)(r >> 16);
}

// Per-block int64/int32 detect: node ids < 50000 => int64 has all-odd-words 0.
__device__ __forceinline__ int detect_stride(const int* __restrict__ ei,
                                             int tid, int* sflag) {
    if (tid < 64) {
        unsigned long long b = __ballot(ei[2 * tid + 1] != 0);
        if (tid == 0) *sflag = b ? 1 : 2;
    }
    __syncthreads();
    return *sflag;
}

// W [K][256] fp32 -> transposed, column-permuted bf16 hi/lo planes [256][K];
// permuted col j = dim*4+head. Also permuted a_src/a_dst.
__device__ __forceinline__ void prepw_one(const float* __restrict__ W,
                                          const float* __restrict__ asrc,
                                          const float* __restrict__ adst,
                                          unsigned short* __restrict__ bhi,
                                          unsigned short* __restrict__ blo,
                                          float* __restrict__ ap,
                                          float* __restrict__ adp,
                                          int K, int t) {
    int j = t / K, k = t - j * K;
    int d = j >> 2, h = j & 3;
    float v = W[k * 256 + h * 64 + d];
    unsigned short hb = bf16_rne(v);
    float hf = __uint_as_float((unsigned)hb << 16);
    bhi[t] = hb;
    blo[t] = bf16_rne(v - hf);
    if (k == 0) { ap[j] = asrc[h * 64 + d]; adp[j] = adst[h * 64 + d]; }
}

// Edge prep (int32 src/dst + self-loops + CLASS-PRIVATIZED degree histogram)
// fused with both layers' weight prep in the tail blocks. Histogram copies
// degc[16][NN] cut same-line RMW serialization 16x (r6 atomic theory test).
__global__ __launch_bounds__(256) void k_prep(
        const int* __restrict__ ei, int* __restrict__ src32,
        int* __restrict__ dst32, int* __restrict__ degc,
        const float* __restrict__ W1, const float* __restrict__ a1s,
        const float* __restrict__ a1d, const float* __restrict__ W2,
        const float* __restrict__ a2s, const float* __restrict__ a2d,
        unsigned short* __restrict__ b1h, unsigned short* __restrict__ b1l,
        unsigned short* __restrict__ b2h, unsigned short* __restrict__ b2l,
        float* __restrict__ ap1, float* __restrict__ adp1,
        float* __restrict__ ap2, float* __restrict__ adp2) {
    int blk = blockIdx.x;
    if (blk >= EB) {  // weight-prep tail
        int g = blk - EB;
        if (g < 128)
            prepw_one(W1, a1s, a1d, b1h, b1l, ap1, adp1, 128, g * 256 + threadIdx.x);
        else
            prepw_one(W2, a2s, a2d, b2h, b2l, ap2, adp2, 64, (g - 128) * 256 + threadIdx.x);
        return;
    }
    __shared__ int sflag;
    int tid = threadIdx.x;
    int st = detect_stride(ei, tid, &sflag);
    int e = blk * 256 + tid;
    if (e >= ETOT) return;
    int s, d;
    if (e < EE) {
        s = ei[(size_t)st * e];
        d = ei[(size_t)st * (EE + e)];
    } else {
        s = d = e - EE;  // self-loop
    }
    src32[e] = s;
    dst32[e] = d;
    atomicAdd(&degc[(size_t)(blk & (NCLS - 1)) * NN + d], 1);
}

// Sum the 16 histogram copies -> combined deg; block-reduce -> bsum.
__global__ __launch_bounds__(256) void k_blocksum(const int* __restrict__ degc,
                                                  int* __restrict__ deg,
                                                  int* __restrict__ bsum) {
    __shared__ int l[256];
    int gid = blockIdx.x * 256 + threadIdx.x;
    int tid = threadIdx.x;
    int s = 0;
    if (gid < NN) {
#pragma unroll
        for (int c = 0; c < NCLS; ++c) s += degc[(size_t)c * NN + gid];
        deg[gid] = s;
    }
    l[tid] = s;
    __syncthreads();
    for (int o = 128; o > 0; o >>= 1) {
        if (tid < o) l[tid] += l[tid + o];
        __syncthreads();
    }
    if (tid == 0) bsum[blockIdx.x] = l[0];
}

// Each block re-scans bsum[196] locally, then scans its 256-chunk of deg.
// Also emits 16 per-class cursor bases cur16[c][d] (exclusive prefix of the
// class counts within each dst) so k_scatter's atomics are class-disjoint.
__global__ __launch_bounds__(256) void k_scan_final(const int* __restrict__ deg,
                                                    const int* __restrict__ bsum,
                                                    int* __restrict__ rowptr,
                                                    const int* __restrict__ degc,
                                                    int* __restrict__ cur16) {
    __shared__ int lb[256];
    __shared__ int l[256];
    int tid = threadIdx.x;
    int vb = (tid < NBLK) ? bsum[tid] : 0;
    lb[tid] = vb;
    __syncthreads();
    for (int d = 1; d < 256; d <<= 1) {
        int t = (tid >= d) ? lb[tid - d] : 0;
        __syncthreads();
        lb[tid] += t;
        __syncthreads();
    }
    int boffb = lb[blockIdx.x] - bsum[blockIdx.x];
    int gid = blockIdx.x * 256 + tid;
    int v = (gid < NN) ? deg[gid] : 0;
    l[tid] = v;
    __syncthreads();
    for (int d = 1; d < 256; d <<= 1) {
        int t = (tid >= d) ? l[tid - d] : 0;
        __syncthreads();
        l[tid] += t;
        __syncthreads();
    }
    int ex = l[tid] - v + boffb;
    if (gid < NN) {
        rowptr[gid] = ex;
        int running = ex;
#pragma unroll
        for (int c = 0; c < NCLS; ++c) {
            cur16[(size_t)c * NN + gid] = running;
            running += degc[(size_t)c * NN + gid];
        }
    }
    if (gid == 0) rowptr[NN] = ETOT;
}

__global__ __launch_bounds__(256) void k_scatter(const int* __restrict__ src32,
                                                 const int* __restrict__ dst32,
                                                 int* __restrict__ cur16,
                                                 int* __restrict__ csr_src) {
    int e = blockIdx.x * 256 + threadIdx.x;
    if (e >= ETOT) return;
    int c = blockIdx.x & (NCLS - 1);
    int pos = atomicAdd(&cur16[(size_t)c * NN + dst32[e]], 1);
    csr_src[pos] = src32[e];
}

// C[M,256] = A[M,K] @ B[K,256] via MFMA 16x16x32 bf16-split (fp32-grade).
// Wave = 32 rows x 16 n-tiles: measured-best config (r12). n-split (r14),
// B-prefetch (r15), and C^T (r16) all regressed -- this shape maximizes
// per-wave B reuse at the occupancy this tiny GEMM can sustain.
template <int K>
__global__ __launch_bounds__(64) void k_gemm_mfma(
        const float* __restrict__ A,
        const unsigned short* __restrict__ Bhi,
        const unsigned short* __restrict__ Blo,
        const float* __restrict__ aperm,
        const float* __restrict__ adperm,
        __half* __restrict__ C16,
        float* __restrict__ os,
        float* __restrict__ od, int M) {
    const int NC = K / 32;
    int lane = threadIdx.x;
    int l = lane & 15, q = lane >> 4;
    int m0 = blockIdx.x * 32;

    bf16x8 ahi[2][NC], alo[2][NC];
#pragma unroll
    for (int t = 0; t < 2; ++t) {
        int row = m0 + t * 16 + l;
        if (row >= M) row = M - 1;  // clamp loads; stores guarded below
        const float* arow = A + (size_t)row * K + q * 8;
#pragma unroll
        for (int c = 0; c < NC; ++c) {
            float4 v0 = *(const float4*)(arow + c * 32);
            float4 v1 = *(const float4*)(arow + c * 32 + 4);
            float vv[8] = {v0.x, v0.y, v0.z, v0.w, v1.x, v1.y, v1.z, v1.w};
#pragma unroll
            for (int j = 0; j < 8; ++j) {
                unsigned short hb = bf16_rne(vv[j]);
                float hf = __uint_as_float((unsigned)hb << 16);
                ahi[t][c][j] = (short)hb;
                alo[t][c][j] = (short)bf16_rne(vv[j] - hf);
            }
        }
    }

    float ps[2][4] = {}, pd[2][4] = {};
    const size_t brow = (size_t)l * K + q * 8;
#pragma unroll 2
    for (int n = 0; n < 16; ++n) {
        const unsigned short* bh = Bhi + (size_t)(n * 16) * K + brow;
        const unsigned short* bl = Blo + (size_t)(n * 16) * K + brow;
        bf16x8 bhf[NC], blf[NC];
#pragma unroll
        for (int c = 0; c < NC; ++c) {
            bhf[c] = *(const bf16x8*)(bh + c * 32);
            blf[c] = *(const bf16x8*)(bl + c * 32);
        }
        f32x4 acc0 = {0.f, 0.f, 0.f, 0.f}, acc1 = {0.f, 0.f, 0.f, 0.f};
#pragma unroll
        for (int c = 0; c < NC; ++c) {
            acc0 = __builtin_amdgcn_mfma_f32_16x16x32_bf16(ahi[0][c], bhf[c], acc0, 0, 0, 0);
            acc1 = __builtin_amdgcn_mfma_f32_16x16x32_bf16(ahi[1][c], bhf[c], acc1, 0, 0, 0);
            acc0 = __builtin_amdgcn_mfma_f32_16x16x32_bf16(ahi[0][c], blf[c], acc0, 0, 0, 0);
            acc1 = __builtin_amdgcn_mfma_f32_16x16x32_bf16(ahi[1][c], blf[c], acc1, 0, 0, 0);
            acc0 = __builtin_amdgcn_mfma_f32_16x16x32_bf16(alo[0][c], bhf[c], acc0, 0, 0, 0);
            acc1 = __builtin_amdgcn_mfma_f32_16x16x32_bf16(alo[1][c], bhf[c], acc1, 0, 0, 0);
        }
        float av = aperm[n * 16 + l], dv = adperm[n * 16 + l];
#pragma unroll
        for (int r = 0; r < 4; ++r) {
            ps[0][r] += acc0[r] * av; pd[0][r] += acc0[r] * dv;
            ps[1][r] += acc1[r] * av; pd[1][r] += acc1[r] * dv;
            int gm0 = m0 + q * 4 + r;
            if (gm0 < M) C16[(size_t)gm0 * 256 + n * 16 + l] = __float2half(acc0[r]);
            int gm1 = m0 + 16 + q * 4 + r;
            if (gm1 < M) C16[(size_t)gm1 * 256 + n * 16 + l] = __float2half(acc1[r]);
        }
    }
#pragma unroll
    for (int t = 0; t < 2; ++t)
#pragma unroll
        for (int r = 0; r < 4; ++r) {
            ps[t][r] += __shfl_xor(ps[t][r], 4);
            ps[t][r] += __shfl_xor(ps[t][r], 8);
            pd[t][r] += __shfl_xor(pd[t][r], 4);
            pd[t][r] += __shfl_xor(pd[t][r], 8);
        }
    if (l < 4) {
#pragma unroll
        for (int t = 0; t < 2; ++t)
#pragma unroll
            for (int r = 0; r < 4; ++r) {
                int gm = m0 + t * 16 + q * 4 + r;
                if (gm < M) {
                    os[(size_t)gm * 4 + l] = ps[t][r];
                    od[(size_t)gm * 4 + l] = pd[t][r];
                }
            }
    }
}

__device__ __forceinline__ float lrelu_exp(float x) {
    x = x > 0.f ? x : 0.2f * x;
    return __expf(x);
}

// Wave per dst node; lane=dim; ONE 8B gather/edge; fdot2 inner op; 4-deep
// pipeline; LDS-staged (s, fp16-alpha). At random-gather fill-path roofline:
// FETCH pinned at 206 MB / ~3.55 TB/s across 5 issue-side variants.
__global__ __launch_bounds__(256) void k_aggr(const int* __restrict__ rowptr,
                                              const int* __restrict__ csr_src,
                                              const float* __restrict__ as_,
                                              const float* __restrict__ ad_,
                                              const __half* __restrict__ h16,
                                              const float* __restrict__ bias,
                                              float* __restrict__ out) {
    __shared__ uint2 als16[4][64];
    __shared__ int sss[4][64];
    int w = threadIdx.x >> 6;
    int lane = threadIdx.x & 63;
    int d = blockIdx.x * 4 + w;
    if (d >= NN) return;
    int beg = rowptr[d], end = rowptr[d + 1];
    float4 adv = *(const float4*)(ad_ + d * 4);

    int s0 = 0;
    float4 u0 = make_float4(0.f, 0.f, 0.f, 0.f);
    float4 den = make_float4(0.f, 0.f, 0.f, 0.f);
    int i0 = beg + lane;
    if (i0 < end) {
        s0 = csr_src[i0];
        float4 sv = *(const float4*)(as_ + s0 * 4);
        u0.x = lrelu_exp(sv.x + adv.x);
        u0.y = lrelu_exp(sv.y + adv.y);
        u0.z = lrelu_exp(sv.z + adv.z);
        u0.w = lrelu_exp(sv.w + adv.w);
        den = u0;
    }
    for (int i = i0 + 64; i < end; i += 64) {
        int s = csr_src[i];
        float4 sv = *(const float4*)(as_ + s * 4);
        den.x += lrelu_exp(sv.x + adv.x);
        den.y += lrelu_exp(sv.y + adv.y);
        den.z += lrelu_exp(sv.z + adv.z);
        den.w += lrelu_exp(sv.w + adv.w);
    }
#pragma unroll
    for (int off = 32; off > 0; off >>= 1) {
        den.x += __shfl_xor(den.x, off);
        den.y += __shfl_xor(den.y, off);
        den.z += __shfl_xor(den.z, off);
        den.w += __shfl_xor(den.w, off);
    }
    float4 dinv = make_float4(0.25f / den.x, 0.25f / den.y,
                              0.25f / den.z, 0.25f / den.w);
    {
        __half2 q0 = __floats2half2_rn(u0.x * dinv.x, u0.y * dinv.y);
        __half2 q1 = __floats2half2_rn(u0.z * dinv.z, u0.w * dinv.w);
        als16[w][lane] = make_uint2(*(unsigned*)&q0, *(unsigned*)&q1);
        sss[w][lane] = s0;
    }

    int cnt = end - beg;
    if (cnt > 64) cnt = 64;
    int cnt4 = (cnt + 3) & ~3;
    float acc = 0.f;
    int4 sq = *(const int4*)&sss[w][0];
    uint2 r0 = *(const uint2*)(h16 + (size_t)sq.x * 256 + lane * 4);
    uint2 r1 = *(const uint2*)(h16 + (size_t)sq.y * 256 + lane * 4);
    uint2 r2 = *(const uint2*)(h16 + (size_t)sq.z * 256 + lane * 4);
    uint2 r3 = *(const uint2*)(h16 + (size_t)sq.w * 256 + lane * 4);
    for (int j = 0; j < cnt4; j += 4) {
        int jn = (j + 4) & 63;
        int4 sn = *(const int4*)&sss[w][jn];
        uint2 n0 = *(const uint2*)(h16 + (size_t)sn.x * 256 + lane * 4);
        uint2 n1 = *(const uint2*)(h16 + (size_t)sn.y * 256 + lane * 4);
        uint2 n2 = *(const uint2*)(h16 + (size_t)sn.z * 256 + lane * 4);
        uint2 n3 = *(const uint2*)(h16 + (size_t)sn.w * 256 + lane * 4);
        uint4 A01 = *(const uint4*)&als16[w][j];
        uint4 A23 = *(const uint4*)&als16[w][j + 2];
        acc = __builtin_amdgcn_fdot2(as_h2(r0.x), as_h2(A01.x), acc, false);
        acc = __builtin_amdgcn_fdot2(as_h2(r0.y), as_h2(A01.y), acc, false);
        acc = __builtin_amdgcn_fdot2(as_h2(r1.x), as_h2(A01.z), acc, false);
        acc = __builtin_amdgcn_fdot2(as_h2(r1.y), as_h2(A01.w), acc, false);
        acc = __builtin_amdgcn_fdot2(as_h2(r2.x), as_h2(A23.x), acc, false);
        acc = __builtin_amdgcn_fdot2(as_h2(r2.y), as_h2(A23.y), acc, false);
        acc = __builtin_amdgcn_fdot2(as_h2(r3.x), as_h2(A23.z), acc, false);
        acc = __builtin_amdgcn_fdot2(as_h2(r3.y), as_h2(A23.w), acc, false);
        r0 = n0; r1 = n1; r2 = n2; r3 = n3;
    }
    for (int chunk = beg + 64; chunk < end; chunk += 64) {
        int i = chunk + lane;
        int s = 0;
        float4 al = make_float4(0.f, 0.f, 0.f, 0.f);
        if (i < end) {
            s = csr_src[i];
            float4 sv = *(const float4*)(as_ + s * 4);
            al.x = lrelu_exp(sv.x + adv.x) * dinv.x;
            al.y = lrelu_exp(sv.y + adv.y) * dinv.y;
            al.z = lrelu_exp(sv.z + adv.z) * dinv.z;
            al.w = lrelu_exp(sv.w + adv.w) * dinv.w;
        }
        int cc = end - chunk;
        if (cc > 64) cc = 64;
        for (int j = 0; j < cc; ++j) {
            int sj = __shfl(s, j);
            float a0 = __shfl(al.x, j), a1 = __shfl(al.y, j);
            float a2 = __shfl(al.z, j), a3 = __shfl(al.w, j);
            uint2 raw = *(const uint2*)(h16 + (size_t)sj * 256 + lane * 4);
            float2 fa = __half22float2(*(const __half2*)&raw.x);
            float2 fb = __half22float2(*(const __half2*)&raw.y);
            acc += a0 * fa.x + a1 * fa.y + a2 * fb.x + a3 * fb.y;
        }
    }
    float v = acc + bias[lane];
    out[d * 64 + lane] = v > 0.f ? v : 0.f;
}

// batch is SORTED: binary-search per graph; 4 waves split the node loop.
__global__ __launch_bounds__(256) void k_pool_fc(const float* __restrict__ x3,
                                                 const int* __restrict__ batch,
                                                 const int* __restrict__ ei,
                                                 const float* __restrict__ fcW,
                                                 const float* __restrict__ fcb,
                                                 float* __restrict__ out) {
    __shared__ int sflag;
    int tid = threadIdx.x, lane = tid & 63, w = tid >> 6;
    int st = detect_stride(ei, tid, &sflag);
    int g = blockIdx.x;
    int lo = 0, hi = NN;
    while (lo < hi) { int mid = (lo + hi) >> 1; if (batch[(size_t)st * mid] < g) lo = mid + 1; else hi = mid; }
    int start = lo;
    hi = NN;
    while (lo < hi) { int mid = (lo + hi) >> 1; if (batch[(size_t)st * mid] < g + 1) lo = mid + 1; else hi = mid; }
    int end = lo;
    float sum = 0.f;
    for (int n = start + w; n < end; n += 4) sum += x3[n * 64 + lane];
    __shared__ float ls[4][64];
    ls[w][lane] = sum;
    __syncthreads();
    if (w == 0) {
        float c = (float)(end - start);
        if (c < 1.f) c = 1.f;
        float p = (ls[0][lane] + ls[1][lane] + ls[2][lane] + ls[3][lane]) / c;
#pragma unroll
        for (int o = 0; o < 16; ++o) {
            float v = p * fcW[lane * 16 + o];
#pragma unroll
            for (int off = 32; off > 0; off >>= 1) v += __shfl_down(v, off);
            if (lane == 0) out[g * 16 + o] = v + fcb[o];
        }
    }
}

extern "C" void kernel_launch(void* const* d_in, const int* in_sizes, int n_in,
                              void* d_out, int out_size, void* d_ws, size_t ws_size,
                              hipStream_t stream) {
    const float* x   = (const float*)d_in[0];
    const int*   ei  = (const int*)d_in[1];
    const int*   bat = (const int*)d_in[2];
    const float* W1  = (const float*)d_in[3];
    const float* a1s = (const float*)d_in[4];
    const float* a1d = (const float*)d_in[5];
    const float* b1  = (const float*)d_in[6];
    const float* W2  = (const float*)d_in[7];
    const float* a2s = (const float*)d_in[8];
    const float* a2d = (const float*)d_in[9];
    const float* b2  = (const float*)d_in[10];
    const float* fcW = (const float*)d_in[11];
    const float* fcb = (const float*)d_in[12];
    float* out = (float*)d_out;

    float* ws = (float*)d_ws;
    __half* h16  = (__half*)(ws + 256);           // [N,256] fp16 [n][dim][head]
    float* as_   = (float*)(h16 + (size_t)NN * 256);  // [N,4]
    float* ad_   = as_ + NN * 4;                  // [N,4]
    float* xacc  = ad_ + NN * 4;                  // [N,64]
    int* src32   = (int*)(xacc + (size_t)NN * 64);// [E]
    int* dst32   = src32 + ETOT;                  // [E]
    int* deg     = dst32 + ETOT;                  // [N] combined
    int* rowptr  = deg + NN;                      // [N+1]
    int* csr_src = rowptr + NN + 1;               // [E]
    int* bsum    = csr_src + ETOT;                // [NBLK]
    char* p = (char*)(bsum + NBLK);
    p = (char*)(((size_t)p + 255) & ~(size_t)255);
    unsigned short* bt1h = (unsigned short*)p; p += 256 * 128 * 2;
    unsigned short* bt1l = (unsigned short*)p; p += 256 * 128 * 2;
    unsigned short* bt2h = (unsigned short*)p; p += 256 * 64 * 2;
    unsigned short* bt2l = (unsigned short*)p; p += 256 * 64 * 2;
    float* ap1  = (float*)p; p += 256 * 4;
    float* adp1 = (float*)p; p += 256 * 4;
    float* ap2  = (float*)p; p += 256 * 4;
    float* adp2 = (float*)p; p += 256 * 4;
    p = (char*)(((size_t)p + 255) & ~(size_t)255);
    int* degc  = (int*)p; p += (size_t)NCLS * NN * 4;  // [16][N] histograms
    int* cur16 = (int*)p; p += (size_t)NCLS * NN * 4;  // [16][N] cursors

    const int wb = (NN * 64 + 255) / 256;  // 12500 wave-per-node blocks

    // ---- one-time per call: indices + dst-CSR + weight planes ----
    hipMemsetAsync(degc, 0, (size_t)NCLS * NN * sizeof(int), stream);
    k_prep<<<EB + 192, 256, 0, stream>>>(ei, src32, dst32, degc,
                                         W1, a1s, a1d, W2, a2s, a2d,
                                         bt1h, bt1l, bt2h, bt2l,
                                         ap1, adp1, ap2, adp2);
    k_blocksum<<<NBLK, 256, 0, stream>>>(degc, deg, bsum);
    k_scan_final<<<NBLK, 256, 0, stream>>>(deg, bsum, rowptr, degc, cur16);
    k_scatter<<<EB, 256, 0, stream>>>(src32, dst32, cur16, csr_src);

    const int gg = (NN + 31) / 32;  // 1563 single-wave blocks, 32 rows each
    // ---- layer 1 ----
    k_gemm_mfma<128><<<gg, 64, 0, stream>>>(x, bt1h, bt1l, ap1, adp1, h16, as_, ad_, NN);
    k_aggr<<<wb, 256, 0, stream>>>(rowptr, csr_src, as_, ad_, h16, b1, xacc);
    // ---- layer 2 ----
    k_gemm_mfma<64><<<gg, 64, 0, stream>>>(xacc, bt2h, bt2l, ap2, adp2, h16, as_, ad_, NN);
    k_aggr<<<wb, 256, 0, stream>>>(rowptr, csr_src, as_, ad_, h16, b2, xacc);
    // ---- pool + fc ----
    k_pool_fc<<<NG, 256, 0, stream>>>(xacc, bat, ei, fcW, fcb, out);
}